// Round 8
// baseline (676.203 us; speedup 1.0000x reference)
//
#include <hip/hip_runtime.h>
#include <cstdint>
#include <cstddef>

// ---- problem constants ----
#define B_N     2
#define L_N     2048
#define DMODEL  512
#define DINNER  1024
#define DSTATE  64
#define NHEADS  16
#define EPROJ   2192      // 2*DINNER + 2*DSTATE + NHEADS
#define PB      2176      // bf16 proj row stride (z,x,B,C)
#define OFF_Z   0
#define OFF_XP  1024
#define OFF_B   2048
#define OFF_C   2112
#define LC      64        // scan chunk length (= matmul tile)
#define NC      32        // L_N / LC
#define NBLK    512       // grid: 2 blocks/CU guaranteed by __launch_bounds__(256,2)

typedef unsigned short u16;
typedef unsigned int   u32;
typedef __attribute__((ext_vector_type(8))) short short8;   // 8 bf16 (4 VGPRs)
typedef __attribute__((ext_vector_type(4))) float floatx4;  // MFMA acc

__device__ __forceinline__ float silu_f(float v) { return v / (1.f + __expf(-v)); }

__device__ __forceinline__ u16 f2bf(float f) {
    union { float f; uint32_t u; } v; v.f = f;
    uint32_t r = (v.u + 0x7FFFu + ((v.u >> 16) & 1u)) >> 16;  // RNE
    return (u16)r;
}

__device__ __forceinline__ float bf2f(u16 b) {
    union { u32 u; float f; } v; v.u = (u32)b << 16; return v.f;
}

__device__ __forceinline__ u32 pack2(float lo, float hi) {
    return (u32)f2bf(lo) | ((u32)f2bf(hi) << 16);
}

__device__ __forceinline__ float lane_bcast(float v, int n) {
    union { float f; uint32_t u; } a, b;
    a.f = v;
    b.u = __builtin_amdgcn_readlane(a.u, n);
    return b.f;
}

// read bf16 fragment A[row][k0..k0+7] from pair-packed LDS tile (stride 33 dwords)
__device__ __forceinline__ short8 frag_ld(const u32* s, int row, int k0) {
    const u32* q = s + row * 33 + (k0 >> 1);
    union { u32 u[4]; short8 v; } r;
    r.u[0] = q[0]; r.u[1] = q[1]; r.u[2] = q[2]; r.u[3] = q[3];
    return r.v;
}

__device__ __forceinline__ void gload_lds16(const u16* g, u16* s) {
    __builtin_amdgcn_global_load_lds(
        (const __attribute__((address_space(1))) void*)g,
        (__attribute__((address_space(3))) void*)s,
        16, 0, 0);
}

// =====================================================================
// Manual grid barrier (device-scope, normal launch; co-residency is
// guaranteed by capacity arithmetic: __launch_bounds__(256,2) ->
// >=2 blocks/CU -> 512 >= NBLK). Monotonic counter, target = k*NBLK.
// =====================================================================
__device__ __forceinline__ void grid_bar(unsigned* cnt, unsigned target) {
    __threadfence();                      // release: flush this XCD's L2
    __syncthreads();
    if (threadIdx.x == 0) {
        __hip_atomic_fetch_add(cnt, 1u, __ATOMIC_RELAXED, __HIP_MEMORY_SCOPE_AGENT);
        while (__hip_atomic_load(cnt, __ATOMIC_RELAXED, __HIP_MEMORY_SCOPE_AGENT) < target)
            __builtin_amdgcn_s_sleep(2);
    }
    __syncthreads();
    __threadfence();                      // acquire: invalidate stale L1/L2
}

// =====================================================================
// GEMM tile (m97 pattern): C = A[M,K] @ Bt[N,K]^T, 4 waves as 2x2.
// PSPLIT: col<2176 -> bf16 Cb (stride 2176); 2176..2191 -> f32 Dt (stride 16).
// =====================================================================
template<int BM, int BN, bool GUARD, bool PSPLIT>
__device__ __forceinline__ void gemm_tile(
    char* lds, const u16* __restrict__ A, const u16* __restrict__ Bt,
    float* __restrict__ Cf, u16* __restrict__ Cb, float* __restrict__ Dt,
    int bx, int by, int M, int N, int K, int tid)
{
    constexpr int MI = BM / 32;
    constexpr int NI = BN / 32;
    u16* As = (u16*)lds;
    u16* Bs = As + BM * 32;

    const int w   = tid >> 6;
    const int ln  = tid & 63;
    const int wm  = w >> 1, wn = w & 1;
    const int bm  = by * BM;
    const int bn  = bx * BN;

    const int srow = ln >> 2;
    const int skq  = (ln & 3) * 8;
    const int fr = ln & 15;
    const int fq = (ln >> 4) * 8;

    floatx4 acc[MI][NI];
    const floatx4 fzero = {0.f, 0.f, 0.f, 0.f};
    #pragma unroll
    for (int mi = 0; mi < MI; ++mi)
        #pragma unroll
        for (int ni = 0; ni < NI; ++ni) acc[mi][ni] = fzero;

    for (int k0 = 0; k0 < K; k0 += 32) {
        #pragma unroll
        for (int r = 0; r < BM / 64; ++r) {
            const int row = r * 64 + w * 16 + srow;
            gload_lds16(A + (size_t)(bm + row) * K + k0 + skq,
                        &As[(r * 64 + w * 16) * 32]);
        }
        #pragma unroll
        for (int r = 0; r < BN / 64; ++r) {
            const int row = r * 64 + w * 16 + srow;
            int rn = bn + row;
            if (GUARD) rn = (rn < N) ? rn : (N - 1);
            gload_lds16(Bt + (size_t)rn * K + k0 + skq,
                        &Bs[(r * 64 + w * 16) * 32]);
        }
        __syncthreads();

        short8 af[MI], bf[NI];
        #pragma unroll
        for (int mi = 0; mi < MI; ++mi)
            af[mi] = *(const short8*)&As[(wm * (BM / 2) + mi * 16 + fr) * 32 + fq];
        #pragma unroll
        for (int ni = 0; ni < NI; ++ni)
            bf[ni] = *(const short8*)&Bs[(wn * (BN / 2) + ni * 16 + fr) * 32 + fq];
        #pragma unroll
        for (int mi = 0; mi < MI; ++mi)
            #pragma unroll
            for (int ni = 0; ni < NI; ++ni)
                acc[mi][ni] = __builtin_amdgcn_mfma_f32_16x16x32_bf16(
                    af[mi], bf[ni], acc[mi][ni], 0, 0, 0);
        __syncthreads();
    }

    const int cr = (ln >> 4) * 4;
    const int cc = ln & 15;
    #pragma unroll
    for (int mi = 0; mi < MI; ++mi) {
        const int row0 = bm + wm * (BM / 2) + mi * 16 + cr;
        #pragma unroll
        for (int ni = 0; ni < NI; ++ni) {
            const int col = bn + wn * (BN / 2) + ni * 16 + cc;
            #pragma unroll
            for (int r = 0; r < 4; ++r) {
                const int row = row0 + r;
                const float v = acc[mi][ni][r];
                if (PSPLIT) {
                    if (col < PB)
                        Cb[(size_t)row * PB + col] = f2bf(v);
                    else if (col < EPROJ)
                        Dt[(size_t)row * 16 + (col - PB)] = v;
                } else {
                    Cf[(size_t)row * N + col] = v;
                }
            }
        }
    }
}

// =====================================================================
// SSD phase-1 tile: conv fused; La=cumsum(logdA); Hc=(e^(La63-La_s)B)^T @ X.
// LDS: sBD[0,8448) sXt[8448,16896) sXr[16896,25472)
// =====================================================================
__device__ __forceinline__ void phase1_tile(
    char* lds, const u16* __restrict__ projb, const float* __restrict__ dtf,
    const float* __restrict__ cw, const float* __restrict__ cb,
    const float* __restrict__ A_log, const float* __restrict__ dt_bias,
    float* __restrict__ hl, float* __restrict__ Pc, float* __restrict__ LaBuf,
    int bid, int tid)
{
    u32* sBD = (u32*)lds;
    u32* sXt = (u32*)(lds + 8448);
    u32* sXr = (u32*)(lds + 16896);
    const u16* sXr16 = (const u16*)sXr;

    const int c = bid & (NC - 1);
    const int h = (bid >> 5) & (NHEADS - 1);
    const int b = bid >> 9;
    const int w = tid >> 6, ln = tid & 63;
    const int a = ln & 15, q = ln >> 4;
    const size_t r0 = (size_t)b * L_N + c * LC;
    const int tl0 = c * LC - 3;

    // logdA + inclusive cumsum (redundant per wave)
    float dt = dtf[(r0 + ln) * 16 + h] + dt_bias[h];
    float sp = (dt > 15.f) ? dt : log1pf(__expf(dt));
    float La = sp * (-__expf(A_log[h]));
    #pragma unroll
    for (int d = 1; d < 64; d <<= 1) {
        float up = __shfl_up(La, d, 64);
        if (ln >= d) La += up;
    }
    if (w == 0) LaBuf[(size_t)bid * 64 + ln] = La;
    const float La63 = lane_bcast(La, 63);

    // stage raw x slice (zero-fill t<0)
    for (int idx = tid; idx < 67 * 32; idx += 256) {
        const int row = idx >> 5, c2 = idx & 31;
        u32 v = 0;
        if (tl0 + row >= 0)
            v = *(const u32*)(projb + ((size_t)b * L_N + tl0 + row) * PB + OFF_XP + h * 64 + 2 * c2);
        sXr[idx] = v;
    }
    __syncthreads();

    const int ch = h * 64 + ln;
    const float4 w4 = *(const float4*)(cw + ch * 4);
    const float bias = cb[ch];

    #pragma unroll
    for (int j = 0; j < 8; ++j) {
        const int sp_ = w * 8 + j, s = sp_ * 2;
        float a0 = bias, a1 = bias;
        #pragma unroll
        for (int k = 0; k < 4; ++k) {
            a0 += bf2f(sXr16[(s + k) * 64 + ln]) * ((const float*)&w4)[k];
            a1 += bf2f(sXr16[(s + 1 + k) * 64 + ln]) * ((const float*)&w4)[k];
        }
        const float x0 = silu_f(a0), x1 = silu_f(a1);
        const float w0 = __expf(La63 - lane_bcast(La, s));
        const float w1 = __expf(La63 - lane_bcast(La, s + 1));
        const float b0 = bf2f(projb[(r0 + s) * PB + OFF_B + ln]) * w0;
        const float b1 = bf2f(projb[(r0 + s + 1) * PB + OFF_B + ln]) * w1;
        sBD[ln * 33 + sp_] = pack2(b0, b1);
        sXt[ln * 33 + sp_] = pack2(x0, x1);
    }
    __syncthreads();

    short8 af[2], bf[4][2];
    #pragma unroll
    for (int ks = 0; ks < 2; ++ks)
        af[ks] = frag_ld(sBD, w * 16 + a, ks * 32 + q * 8);
    #pragma unroll
    for (int tn = 0; tn < 4; ++tn)
        #pragma unroll
        for (int ks = 0; ks < 2; ++ks)
            bf[tn][ks] = frag_ld(sXt, tn * 16 + a, ks * 32 + q * 8);

    const floatx4 fzero = {0.f, 0.f, 0.f, 0.f};
    floatx4 acc[4];
    #pragma unroll
    for (int tn = 0; tn < 4; ++tn) {
        acc[tn] = fzero;
        #pragma unroll
        for (int ks = 0; ks < 2; ++ks)
            acc[tn] = __builtin_amdgcn_mfma_f32_16x16x32_bf16(
                af[ks], bf[tn][ks], acc[tn], 0, 0, 0);
    }

    float* hp = hl + (size_t)bid * (DSTATE * 64);
    #pragma unroll
    for (int tn = 0; tn < 4; ++tn)
        #pragma unroll
        for (int r = 0; r < 4; ++r)
            hp[(w * 16 + q * 4 + r) * 64 + tn * 16 + a] = acc[tn][r];
    if (tid == 0) Pc[bid] = __expf(La63);
    __syncthreads();   // LDS reuse fence before next tile's staging
}

// =====================================================================
// SSD phase-2: element-parallel inter-chunk carry, in place over hl.
// =====================================================================
__device__ __forceinline__ void phase2_work(
    float* __restrict__ hl, const float* __restrict__ Pc, int bid, int tid)
{
    const int bh = bid >> 4;
    const int e = (bid & 15) * 256 + tid;

    float carry = 0.f;
    float nxt = hl[(size_t)(bh * NC) * 4096 + e];
    for (int c = 0; c < NC; ++c) {
        const int slot = bh * NC + c;
        const float cur = nxt;
        if (c + 1 < NC) nxt = hl[(size_t)(slot + 1) * 4096 + e];
        const float Pv = Pc[slot];
        hl[(size_t)slot * 4096 + e] = carry;
        carry = fmaf(Pv, carry, cur);
    }
}

// =====================================================================
// SSD phase-3 tile: conv fused; S^T=B@C; W=S*decay*mask;
// Y = diag(e^La) C@h_start^T + W@X^T; yz = Y*silu(z).
// LDS: sBW[0,8448) sC[8448,16896) sXt[16896,25344) sLaF[25344,25600)
//      sXr[25600,34176); sH aliases sXr (staged after conv);
//      sY aliases sC+sXt (epilogue only).
// =====================================================================
__device__ __forceinline__ void phase3_tile(
    char* lds, const u16* __restrict__ projb,
    const float* __restrict__ cw, const float* __restrict__ cb,
    const float* __restrict__ hl, const float* __restrict__ LaBuf,
    u16* __restrict__ yz, int bid, int tid)
{
    u32* sBW    = (u32*)lds;
    u32* sC     = (u32*)(lds + 8448);
    u32* sXt    = (u32*)(lds + 16896);
    float* sLaF = (float*)(lds + 25344);
    u32* sXr    = (u32*)(lds + 25600);
    u32* sH     = (u32*)(lds + 25600);   // aliases sXr (staged after conv)
    float* sY   = (float*)(lds + 8448);  // aliases sC+sXt (epilogue)
    const u16* sXr16 = (const u16*)sXr;

    const int c = bid & (NC - 1);
    const int h = (bid >> 5) & (NHEADS - 1);
    const int b = bid >> 9;
    const int w = tid >> 6, ln = tid & 63;
    const int a = ln & 15, q = ln >> 4;
    const int hw = ln >> 5, k32 = ln & 31;
    const size_t r0 = (size_t)b * L_N + c * LC;
    const int tl0 = c * LC - 3;

    if (tid < 64) sLaF[tid] = LaBuf[(size_t)bid * 64 + tid];

    for (int idx = tid; idx < 67 * 32; idx += 256) {
        const int row = idx >> 5, c2 = idx & 31;
        u32 v = 0;
        if (tl0 + row >= 0)
            v = *(const u32*)(projb + ((size_t)b * L_N + tl0 + row) * PB + OFF_XP + h * 64 + 2 * c2);
        sXr[idx] = v;
    }
    __syncthreads();                       // sync A

    const int ch = h * 64 + ln;
    const float4 w4 = *(const float4*)(cw + ch * 4);
    const float bias = cb[ch];

    #pragma unroll
    for (int j = 0; j < 8; ++j) {
        const int rp = w * 8 + j;
        const int row = rp * 2 + hw;
        sBW[row * 33 + k32] = *(const u32*)(projb + (r0 + row) * PB + OFF_B + 2 * k32);
        sC [row * 33 + k32] = *(const u32*)(projb + (r0 + row) * PB + OFF_C + 2 * k32);

        const int s = rp * 2;
        float a0 = bias, a1 = bias;
        #pragma unroll
        for (int k = 0; k < 4; ++k) {
            a0 += bf2f(sXr16[(s + k) * 64 + ln]) * ((const float*)&w4)[k];
            a1 += bf2f(sXr16[(s + 1 + k) * 64 + ln]) * ((const float*)&w4)[k];
        }
        sXt[ln * 33 + rp] = pack2(silu_f(a0), silu_f(a1));
    }
    __syncthreads();                       // sync B: sXr reads done; staging visible

    // stage h_start^T into sXr region (all raw-x reads complete)
    const float* hs = hl + (size_t)bid * 4096;
    #pragma unroll
    for (int j = 0; j < 8; ++j) {
        const int rp = w * 8 + j;
        sH[ln * 33 + rp] = pack2(hs[(2 * rp) * 64 + ln], hs[(2 * rp + 1) * 64 + ln]);
    }

    const floatx4 fzero = {0.f, 0.f, 0.f, 0.f};

    // ---- m1: S^T tiles [tm][tn=w], tm<=w ----
    short8 cfr[2], bfr[4][2];
    #pragma unroll
    for (int ks = 0; ks < 2; ++ks)
        cfr[ks] = frag_ld(sC, w * 16 + a, ks * 32 + q * 8);
    #pragma unroll
    for (int tm = 0; tm < 4; ++tm)
        if (tm <= w)
            #pragma unroll
            for (int ks = 0; ks < 2; ++ks)
                bfr[tm][ks] = frag_ld(sBW, tm * 16 + a, ks * 32 + q * 8);
    floatx4 accS[4];
    #pragma unroll
    for (int tm = 0; tm < 4; ++tm) {
        if (tm > w) continue;
        accS[tm] = fzero;
        #pragma unroll
        for (int ks = 0; ks < 2; ++ks)
            accS[tm] = __builtin_amdgcn_mfma_f32_16x16x32_bf16(
                bfr[tm][ks], cfr[ks], accS[tm], 0, 0, 0);
    }
    __syncthreads();   // sync C: B reads done (W overwrite safe); sH visible

    // ---- build W rows i in [16w,16w+16) ----
    {
        const int i = w * 16 + a;
        const float Li = sLaF[i];
        #pragma unroll
        for (int tm = 0; tm < 4; ++tm) {
            const int d0 = i * 33 + tm * 8 + q * 2;
            if (tm > w) {
                sBW[d0] = 0; sBW[d0 + 1] = 0;
            } else {
                const float4 Ls = *(const float4*)(sLaF + tm * 16 + q * 4);
                float v[4];
                #pragma unroll
                for (int r = 0; r < 4; ++r) {
                    const int s = tm * 16 + q * 4 + r;
                    const float ww = (s <= i) ? __expf(Li - ((const float*)&Ls)[r]) : 0.f;
                    v[r] = accS[tm][r] * ww;
                }
                sBW[d0]     = pack2(v[0], v[1]);
                sBW[d0 + 1] = pack2(v[2], v[3]);
            }
        }
    }

    // ---- m4: accY = C @ h_start^T (row-tile w), scale rows by e^La_i ----
    short8 hfr[4][2];
    #pragma unroll
    for (int tp = 0; tp < 4; ++tp)
        #pragma unroll
        for (int ks = 0; ks < 2; ++ks)
            hfr[tp][ks] = frag_ld(sH, tp * 16 + a, ks * 32 + q * 8);
    floatx4 accY[4];
    #pragma unroll
    for (int tp = 0; tp < 4; ++tp) {
        accY[tp] = fzero;
        #pragma unroll
        for (int ks = 0; ks < 2; ++ks)
            accY[tp] = __builtin_amdgcn_mfma_f32_16x16x32_bf16(
                cfr[ks], hfr[tp][ks], accY[tp], 0, 0, 0);
    }
    {
        const float4 Ls = *(const float4*)(sLaF + w * 16 + q * 4);
        float e4[4];
        #pragma unroll
        for (int r = 0; r < 4; ++r) e4[r] = __expf(((const float*)&Ls)[r]);
        #pragma unroll
        for (int tp = 0; tp < 4; ++tp)
            #pragma unroll
            for (int r = 0; r < 4; ++r) accY[tp][r] *= e4[r];
    }

    // ---- m2: accY += W @ X^T (wave reads only its own W rows) ----
    short8 wfr[2], xfr[4][2];
    #pragma unroll
    for (int ks = 0; ks < 2; ++ks)
        wfr[ks] = frag_ld(sBW, w * 16 + a, ks * 32 + q * 8);
    #pragma unroll
    for (int tp = 0; tp < 4; ++tp)
        #pragma unroll
        for (int ks = 0; ks < 2; ++ks)
            xfr[tp][ks] = frag_ld(sXt, tp * 16 + a, ks * 32 + q * 8);
    #pragma unroll
    for (int tp = 0; tp < 4; ++tp)
        #pragma unroll
        for (int ks = 0; ks < 2; ++ks)
            accY[tp] = __builtin_amdgcn_mfma_f32_16x16x32_bf16(
                wfr[ks], xfr[tp][ks], accY[tp], 0, 0, 0);
    __syncthreads();   // all sC/sXt frag reads done; safe to alias as sY

    // ---- epilogue: own-rows LDS round-trip, gate (bf16 z), bf16 store ----
    #pragma unroll
    for (int tp = 0; tp < 4; ++tp)
        #pragma unroll
        for (int r = 0; r < 4; ++r)
            sY[(w * 16 + q * 4 + r) * 66 + tp * 16 + a] = accY[tp][r];
    #pragma unroll
    for (int ii = 0; ii < 16; ++ii) {
        const int i = w * 16 + ii;
        const float y = sY[i * 66 + ln];
        const float z = bf2f(projb[(r0 + i) * PB + OFF_Z + h * 64 + ln]);
        yz[(r0 + i) * DINNER + h * 64 + ln] = f2bf(y * silu_f(z));
    }
    __syncthreads();   // LDS reuse fence before next tile's staging
}

// =====================================================================
// Persistent mega-kernel: all 6 stages, 5 manual grid barriers.
// grid = 512 x 256 thr; __launch_bounds__(256,2) -> >=2 blocks/CU ->
// capacity 512 >= grid (co-resident by construction). LDS 34,176 B.
// =====================================================================
__global__ __launch_bounds__(256, 2) void mamba2_mega(
    const float* __restrict__ x, const float* __restrict__ W_in,
    const float* __restrict__ conv_w, const float* __restrict__ conv_b,
    const float* __restrict__ A_log, const float* __restrict__ dt_bias,
    const float* __restrict__ W_out, float* __restrict__ out,
    u16* __restrict__ projb, float* __restrict__ dtf,
    float* __restrict__ hl, float* __restrict__ Pc, float* __restrict__ LaBuf,
    u16* __restrict__ xbf, u16* __restrict__ wibf, u16* __restrict__ wobf,
    u16* __restrict__ yzbf, unsigned* __restrict__ barc)
{
    __shared__ __align__(16) char lds[34176];

    const int bid = blockIdx.x;
    const int tid = threadIdx.x;

    // ---- stage 0: fused bf16 casts (grid-stride over float4 quads) ----
    {
        const int n0 = 4096 * DMODEL / 4, n1 = EPROJ * DMODEL / 4, n2 = DMODEL * DINNER / 4;
        const int ntot = n0 + n1 + n2;
        for (int i = bid * 256 + tid; i < ntot; i += NBLK * 256) {
            int j = i; const float* s; u16* d;
            if (j < n0)           { s = x; d = xbf; }
            else if (j < n0 + n1) { j -= n0; s = W_in; d = wibf; }
            else                  { j -= n0 + n1; s = W_out; d = wobf; }
            float4 v = ((const float4*)s)[j];
            ushort4 o;
            o.x = f2bf(v.x); o.y = f2bf(v.y); o.z = f2bf(v.z); o.w = f2bf(v.w);
            ((ushort4*)d)[j] = o;
        }
    }
    grid_bar(barc, NBLK * 1);

    // ---- stage 1: in_proj GEMM, 576 tiles (18 x 32), grid-stride ----
    for (int t = bid; t < 576; t += NBLK)
        gemm_tile<128, 128, true, true>(lds, xbf, wibf, nullptr, projb, dtf,
                                        t % 18, t / 18, 4096, EPROJ, DMODEL, tid);
    grid_bar(barc, NBLK * 2);

    // ---- stage 2: SSD phase 1, 1024 tiles ----
    for (int t = bid; t < 1024; t += NBLK)
        phase1_tile(lds, projb, dtf, conv_w, conv_b, A_log, dt_bias,
                    hl, Pc, LaBuf, t, tid);
    grid_bar(barc, NBLK * 3);

    // ---- stage 3: SSD phase 2 (inter-chunk carry), 512 work blocks ----
    phase2_work(hl, Pc, bid, tid);
    grid_bar(barc, NBLK * 4);

    // ---- stage 4: SSD phase 3, 1024 tiles ----
    for (int t = bid; t < 1024; t += NBLK)
        phase3_tile(lds, projb, conv_w, conv_b, hl, LaBuf, yzbf, t, tid);
    grid_bar(barc, NBLK * 5);

    // ---- stage 5: out_proj GEMM, 512 tiles (8 x 64) ----
    for (int t = bid; t < 512; t += NBLK)
        gemm_tile<64, 64, false, false>(lds, yzbf, wobf, out, nullptr, nullptr,
                                        t % 8, t / 8, 4096, DMODEL, DINNER, tid);
}

// =====================================================================
extern "C" void kernel_launch(void* const* d_in, const int* in_sizes, int n_in,
                              void* d_out, int out_size, void* d_ws, size_t ws_size,
                              hipStream_t stream)
{
    const float* x       = (const float*)d_in[0];
    const float* W_in    = (const float*)d_in[1];
    const float* conv_w  = (const float*)d_in[2];
    const float* conv_b  = (const float*)d_in[3];
    const float* A_log   = (const float*)d_in[4];
    const float* dt_bias = (const float*)d_in[5];
    const float* W_out   = (const float*)d_in[6];
    float* out = (float*)d_out;

    // workspace layout (~51 MB)
    u16*   projb = (u16*)d_ws;                                  // 4096*2176 bf16
    float* dtf   = (float*)(projb + (size_t)4096 * PB);         // 4096*16 f32
    float* hl    = dtf + (size_t)4096 * 16;                     // 1024*4096 f32
    float* Pc    = hl + (size_t)1024 * 4096;                    // 1024
    float* LaBuf = Pc + 1024;                                   // 1024*64
    u16*   xbf   = (u16*)(LaBuf + 1024 * 64);                   // 4096*512 bf16
    u16*   wibf  = xbf + (size_t)4096 * DMODEL;                 // 2192*512 bf16
    u16*   wobf  = wibf + (size_t)EPROJ * DMODEL;               // 512*1024 bf16
    u16*   yzbf  = wobf + (size_t)DMODEL * DINNER;              // 4096*1024 bf16
    unsigned* barc = (unsigned*)(yzbf + (size_t)4096 * DINNER); // barrier counter

    hipMemsetAsync(barc, 0, 64, stream);

    mamba2_mega<<<dim3(NBLK), dim3(256), 0, stream>>>(
        x, W_in, conv_w, conv_b, A_log, dt_bias, W_out, out,
        projb, dtf, hl, Pc, LaBuf, xbf, wibf, wobf, yzbf, barc);
}

// Round 9
// 156.592 us; speedup vs baseline: 4.3183x; 4.3183x over previous
//
#include <hip/hip_runtime.h>
#include <cstdint>
#include <cstddef>

// ---- problem constants ----
#define B_N     2
#define L_N     2048
#define DMODEL  512
#define DINNER  1024
#define DSTATE  64
#define NHEADS  16
#define EPROJ   2192      // 2*DINNER + 2*DSTATE + NHEADS
#define PB      2176      // bf16 proj row stride (z,x,B,C)
#define OFF_Z   0
#define OFF_XP  1024
#define OFF_B   2048
#define OFF_C   2112
#define LC      64        // scan chunk length (= matmul tile)
#define NC      32        // L_N / LC

typedef unsigned short u16;
typedef unsigned int   u32;
typedef __attribute__((ext_vector_type(8))) short short8;   // 8 bf16 (4 VGPRs)
typedef __attribute__((ext_vector_type(4))) float floatx4;  // MFMA acc

__device__ __forceinline__ float silu_f(float v) { return v / (1.f + __expf(-v)); }

__device__ __forceinline__ u16 f2bf(float f) {
    union { float f; uint32_t u; } v; v.f = f;
    uint32_t r = (v.u + 0x7FFFu + ((v.u >> 16) & 1u)) >> 16;  // RNE
    return (u16)r;
}

__device__ __forceinline__ float bf2f(u16 b) {
    union { u32 u; float f; } v; v.u = (u32)b << 16; return v.f;
}

__device__ __forceinline__ u32 pack2(float lo, float hi) {
    return (u32)f2bf(lo) | ((u32)f2bf(hi) << 16);
}

__device__ __forceinline__ float lane_bcast(float v, int n) {
    union { float f; uint32_t u; } a, b;
    a.f = v;
    b.u = __builtin_amdgcn_readlane(a.u, n);
    return b.f;
}

// read bf16 fragment A[row][k0..k0+7] from pair-packed LDS tile (stride 33 dwords)
__device__ __forceinline__ short8 frag_ld(const u32* s, int row, int k0) {
    const u32* q = s + row * 33 + (k0 >> 1);
    union { u32 u[4]; short8 v; } r;
    r.u[0] = q[0]; r.u[1] = q[1]; r.u[2] = q[2]; r.u[3] = q[3];
    return r.v;
}

__device__ __forceinline__ void gload_lds16(const u16* g, u16* s) {
    __builtin_amdgcn_global_load_lds(
        (const __attribute__((address_space(1))) void*)g,
        (__attribute__((address_space(3))) void*)s,
        16, 0, 0);
}

// =====================================================================
// fused fp32 -> bf16 cast for x, W_in, W_out (one launch). n's in float4 quads.
// =====================================================================
__global__ __launch_bounds__(256) void cast3_kern(
    const float* __restrict__ s0, u16* __restrict__ d0, int n0,
    const float* __restrict__ s1, u16* __restrict__ d1, int n1,
    const float* __restrict__ s2, u16* __restrict__ d2, int n2)
{
    int i = blockIdx.x * 256 + threadIdx.x;
    const float* s; u16* d;
    if (i < n0)           { s = s0; d = d0; }
    else if (i < n0 + n1) { i -= n0; s = s1; d = d1; }
    else                  { i -= n0 + n1; if (i >= n2) return; s = s2; d = d2; }
    float4 v = ((const float4*)s)[i];
    ushort4 o;
    o.x = f2bf(v.x); o.y = f2bf(v.y); o.z = f2bf(v.z); o.w = f2bf(v.w);
    ((ushort4*)d)[i] = o;
}

// =====================================================================
// bf16 MFMA GEMM, generalized (m97 pattern).
//   C = A[M,K] @ Bt[N,K]^T.  4 waves as 2x2; wave tile (BM/2)x(BN/2).
// PSPLIT epilogue: col<2176 -> bf16 projb (stride 2176);
//                  2176<=col<2192 -> f32 dtf (stride 16). Else f32 Cf[M,N].
// =====================================================================
template<int BM, int BN, bool GUARD, bool PSPLIT>
__global__ __launch_bounds__(256) void gemm_mfma_bt(
    const u16* __restrict__ A, const u16* __restrict__ Bt,
    float* __restrict__ Cf, u16* __restrict__ Cb, float* __restrict__ Dt,
    int M, int N, int K)
{
    constexpr int MI = BM / 32;
    constexpr int NI = BN / 32;
    __shared__ u16 As[BM * 32];
    __shared__ u16 Bs[BN * 32];

    const int tid = threadIdx.x;
    const int w   = tid >> 6;
    const int ln  = tid & 63;
    const int wm  = w >> 1, wn = w & 1;
    const int bm  = blockIdx.y * BM;
    const int bn  = blockIdx.x * BN;

    const int srow = ln >> 2;
    const int skq  = (ln & 3) * 8;
    const int fr = ln & 15;
    const int fq = (ln >> 4) * 8;

    floatx4 acc[MI][NI];
    const floatx4 fzero = {0.f, 0.f, 0.f, 0.f};
    #pragma unroll
    for (int mi = 0; mi < MI; ++mi)
        #pragma unroll
        for (int ni = 0; ni < NI; ++ni) acc[mi][ni] = fzero;

    for (int k0 = 0; k0 < K; k0 += 32) {
        #pragma unroll
        for (int r = 0; r < BM / 64; ++r) {
            const int row = r * 64 + w * 16 + srow;
            gload_lds16(A + (size_t)(bm + row) * K + k0 + skq,
                        &As[(r * 64 + w * 16) * 32]);
        }
        #pragma unroll
        for (int r = 0; r < BN / 64; ++r) {
            const int row = r * 64 + w * 16 + srow;
            int rn = bn + row;
            if (GUARD) rn = (rn < N) ? rn : (N - 1);
            gload_lds16(Bt + (size_t)rn * K + k0 + skq,
                        &Bs[(r * 64 + w * 16) * 32]);
        }
        __syncthreads();

        short8 af[MI], bf[NI];
        #pragma unroll
        for (int mi = 0; mi < MI; ++mi)
            af[mi] = *(const short8*)&As[(wm * (BM / 2) + mi * 16 + fr) * 32 + fq];
        #pragma unroll
        for (int ni = 0; ni < NI; ++ni)
            bf[ni] = *(const short8*)&Bs[(wn * (BN / 2) + ni * 16 + fr) * 32 + fq];
        #pragma unroll
        for (int mi = 0; mi < MI; ++mi)
            #pragma unroll
            for (int ni = 0; ni < NI; ++ni)
                acc[mi][ni] = __builtin_amdgcn_mfma_f32_16x16x32_bf16(
                    af[mi], bf[ni], acc[mi][ni], 0, 0, 0);
        __syncthreads();
    }

    const int cr = (ln >> 4) * 4;
    const int cc = ln & 15;
    #pragma unroll
    for (int mi = 0; mi < MI; ++mi) {
        const int row0 = bm + wm * (BM / 2) + mi * 16 + cr;
        #pragma unroll
        for (int ni = 0; ni < NI; ++ni) {
            const int col = bn + wn * (BN / 2) + ni * 16 + cc;
            #pragma unroll
            for (int r = 0; r < 4; ++r) {
                const int row = row0 + r;
                const float v = acc[mi][ni][r];
                if (PSPLIT) {
                    if (col < PB)
                        Cb[(size_t)row * PB + col] = f2bf(v);
                    else if (col < EPROJ)
                        Dt[(size_t)row * 16 + (col - PB)] = v;
                } else {
                    Cf[(size_t)row * N + col] = v;
                }
            }
        }
    }
}

// =====================================================================
// SSD phase 1 — 4-wave cooperative block per (b,h,chunk), conv fused:
//   stage raw x slice (67x64 bf16) -> conv+silu during X^T pack;
//   La = cumsum(logdA);  Hc = (e^(La63-La_s) B)^T @ X  (MFMA)
// =====================================================================
__global__ __launch_bounds__(256) void ssd_phase1(
    const u16* __restrict__ projb, const float* __restrict__ dtf,
    const float* __restrict__ cw, const float* __restrict__ cb,
    const float* __restrict__ A_log, const float* __restrict__ dt_bias,
    float* __restrict__ hl, float* __restrict__ Pc, float* __restrict__ LaBuf)
{
    __shared__ u32 sBD[64 * 33];   // (e^(La63-La_s) B[s][n])^T : [n][s-pair]
    __shared__ u32 sXt[64 * 33];   // X^T: [p][s-pair]
    __shared__ u32 sXr[67 * 32];   // raw x rows r0-3..r0+63 (bf16 pairs)
    const u16* sXr16 = (const u16*)sXr;

    const int bid = blockIdx.x;               // ((b*16+h)*32 + c)
    const int c = bid & (NC - 1);
    const int h = (bid >> 5) & (NHEADS - 1);
    const int b = bid >> 9;
    const int tid = threadIdx.x;
    const int w = tid >> 6, ln = tid & 63;
    const int a = ln & 15, q = ln >> 4;
    const size_t r0 = (size_t)b * L_N + c * LC;
    const int tl0 = c * LC - 3;               // local time of LDS row 0

    // logdA + inclusive cumsum (redundant per wave; all waves identical)
    float dt = dtf[(r0 + ln) * 16 + h] + dt_bias[h];
    float sp = (dt > 15.f) ? dt : log1pf(__expf(dt));
    float La = sp * (-__expf(A_log[h]));
    #pragma unroll
    for (int d = 1; d < 64; d <<= 1) {
        float up = __shfl_up(La, d, 64);
        if (ln >= d) La += up;
    }
    if (w == 0) LaBuf[(size_t)bid * 64 + ln] = La;
    const float La63 = lane_bcast(La, 63);

    // stage raw x slice (zero-fill t<0)
    for (int idx = tid; idx < 67 * 32; idx += 256) {
        const int row = idx >> 5, c2 = idx & 31;
        u32 v = 0;
        if (tl0 + row >= 0)
            v = *(const u32*)(projb + ((size_t)b * L_N + tl0 + row) * PB + OFF_XP + h * 64 + 2 * c2);
        sXr[idx] = v;
    }
    __syncthreads();

    const int ch = h * 64 + ln;
    const float4 w4 = *(const float4*)(cw + ch * 4);
    const float bias = cb[ch];

    // staging: wave w covers s-pairs [w*8, w*8+8); conv+silu inline
    #pragma unroll
    for (int j = 0; j < 8; ++j) {
        const int sp_ = w * 8 + j, s = sp_ * 2;
        float a0 = bias, a1 = bias;
        #pragma unroll
        for (int k = 0; k < 4; ++k) {
            a0 += bf2f(sXr16[(s + k) * 64 + ln]) * ((const float*)&w4)[k];
            a1 += bf2f(sXr16[(s + 1 + k) * 64 + ln]) * ((const float*)&w4)[k];
        }
        const float x0 = silu_f(a0), x1 = silu_f(a1);
        const float w0 = __expf(La63 - lane_bcast(La, s));
        const float w1 = __expf(La63 - lane_bcast(La, s + 1));
        const float b0 = bf2f(projb[(r0 + s) * PB + OFF_B + ln]) * w0;
        const float b1 = bf2f(projb[(r0 + s + 1) * PB + OFF_B + ln]) * w1;
        sBD[ln * 33 + sp_] = pack2(b0, b1);
        sXt[ln * 33 + sp_] = pack2(x0, x1);
    }
    __syncthreads();

    // MFMA: wave w computes output tile-row tm=w (rows n in [16w,16w+16))
    short8 af[2], bf[4][2];
    #pragma unroll
    for (int ks = 0; ks < 2; ++ks)
        af[ks] = frag_ld(sBD, w * 16 + a, ks * 32 + q * 8);
    #pragma unroll
    for (int tn = 0; tn < 4; ++tn)
        #pragma unroll
        for (int ks = 0; ks < 2; ++ks)
            bf[tn][ks] = frag_ld(sXt, tn * 16 + a, ks * 32 + q * 8);

    const floatx4 fzero = {0.f, 0.f, 0.f, 0.f};
    floatx4 acc[4];
    #pragma unroll
    for (int tn = 0; tn < 4; ++tn) {
        acc[tn] = fzero;
        #pragma unroll
        for (int ks = 0; ks < 2; ++ks)
            acc[tn] = __builtin_amdgcn_mfma_f32_16x16x32_bf16(
                af[ks], bf[tn][ks], acc[tn], 0, 0, 0);
    }

    float* hp = hl + (size_t)bid * (DSTATE * 64);
    #pragma unroll
    for (int tn = 0; tn < 4; ++tn)
        #pragma unroll
        for (int r = 0; r < 4; ++r)
            hp[(w * 16 + q * 4 + r) * 64 + tn * 16 + a] = acc[tn][r];
    if (tid == 0) Pc[bid] = __expf(La63);
}

// =====================================================================
// SSD phase 2 — element-parallel inter-chunk carry, in place over hl.
// All 32 chunk loads are independent: issue upfront into registers,
// scan in-registers, store back. Bandwidth-bound (~34 MB), not latency.
// =====================================================================
__global__ __launch_bounds__(256) void ssd_phase2(
    float* __restrict__ hl, const float* __restrict__ Pc)
{
    const int bid = blockIdx.x;               // bh*16 + eg
    const int bh = bid >> 4;
    const int e = (bid & 15) * 256 + threadIdx.x;   // state element 0..4095
    const size_t base = (size_t)(bh * NC) * 4096 + e;

    float v[NC];
    #pragma unroll
    for (int c = 0; c < NC; ++c)
        v[c] = hl[base + (size_t)c * 4096];

    float carry = 0.f;
    #pragma unroll
    for (int c = 0; c < NC; ++c) {
        const float cur = v[c];
        v[c] = carry;                          // h_start entering chunk c
        carry = fmaf(Pc[bh * NC + c], carry, cur);
    }

    #pragma unroll
    for (int c = 0; c < NC; ++c)
        hl[base + (size_t)c * 4096] = v[c];
}

// =====================================================================
// SSD phase 3 — 4-wave cooperative block per (b,h,chunk), conv fused:
//   S^T = B @ C;  W[i][s] = S[i,s] e^(La_i-La_s) (s<=i)
//   Y = diag(e^La) C @ h_start^T + W @ X^T;  yz = Y * silu(z)
// =====================================================================
__global__ __launch_bounds__(256) void ssd_phase3(
    const u16* __restrict__ projb,
    const float* __restrict__ cw, const float* __restrict__ cb,
    const float* __restrict__ hl, const float* __restrict__ LaBuf,
    u16* __restrict__ yz)
{
    __shared__ char lds[42624];
    u32* sBW   = (u32*)lds;              // B natural, then W (aliased)
    u32* sC    = (u32*)(lds + 8448);     // C natural [i][n-pair]
    u32* sXt   = (u32*)(lds + 16896);    // X^T [p][s-pair]
    u32* sH    = (u32*)(lds + 25344);    // h_start^T [p][n-pair]
    float* sLaF = (float*)(lds + 33792); // La[64]
    u32* sXr   = (u32*)(lds + 34048);    // raw x rows r0-3..r0+63
    float* sY  = (float*)(lds + 8448);   // f32 [i][p] 64x66, aliases sC+sXt (epilogue)
    const u16* sXr16 = (const u16*)sXr;

    const int bid = blockIdx.x;
    const int c = bid & (NC - 1);
    const int h = (bid >> 5) & (NHEADS - 1);
    const int b = bid >> 9;
    const int tid = threadIdx.x;
    const int w = tid >> 6, ln = tid & 63;
    const int a = ln & 15, q = ln >> 4;
    const int hw = ln >> 5, k32 = ln & 31;
    const size_t r0 = (size_t)b * L_N + c * LC;
    const int tl0 = c * LC - 3;

    if (tid < 64) sLaF[tid] = LaBuf[(size_t)bid * 64 + tid];

    // stage raw x slice
    for (int idx = tid; idx < 67 * 32; idx += 256) {
        const int row = idx >> 5, c2 = idx & 31;
        u32 v = 0;
        if (tl0 + row >= 0)
            v = *(const u32*)(projb + ((size_t)b * L_N + tl0 + row) * PB + OFF_XP + h * 64 + 2 * c2);
        sXr[idx] = v;
    }
    __syncthreads();

    const int ch = h * 64 + ln;
    const float4 w4 = *(const float4*)(cw + ch * 4);
    const float bias = cb[ch];

    // stage B, C natural (raw bf16-pair copies); X^T (conv inline), H^T pack
    const float* hs = hl + (size_t)bid * 4096;
    #pragma unroll
    for (int j = 0; j < 8; ++j) {
        const int rp = w * 8 + j;
        const int row = rp * 2 + hw;
        sBW[row * 33 + k32] = *(const u32*)(projb + (r0 + row) * PB + OFF_B + 2 * k32);
        sC [row * 33 + k32] = *(const u32*)(projb + (r0 + row) * PB + OFF_C + 2 * k32);

        const int s = rp * 2;
        float a0 = bias, a1 = bias;
        #pragma unroll
        for (int k = 0; k < 4; ++k) {
            a0 += bf2f(sXr16[(s + k) * 64 + ln]) * ((const float*)&w4)[k];
            a1 += bf2f(sXr16[(s + 1 + k) * 64 + ln]) * ((const float*)&w4)[k];
        }
        sXt[ln * 33 + rp] = pack2(silu_f(a0), silu_f(a1));

        sH[ln * 33 + rp] = pack2(hs[(2 * rp) * 64 + ln], hs[(2 * rp + 1) * 64 + ln]);
    }
    __syncthreads();

    const floatx4 fzero = {0.f, 0.f, 0.f, 0.f};

    // ---- m1: S^T tiles [tm][tn=w], tm<=w ----
    short8 cfr[2], bfr[4][2];
    #pragma unroll
    for (int ks = 0; ks < 2; ++ks)
        cfr[ks] = frag_ld(sC, w * 16 + a, ks * 32 + q * 8);
    #pragma unroll
    for (int tm = 0; tm < 4; ++tm)
        if (tm <= w)
            #pragma unroll
            for (int ks = 0; ks < 2; ++ks)
                bfr[tm][ks] = frag_ld(sBW, tm * 16 + a, ks * 32 + q * 8);
    floatx4 accS[4];
    #pragma unroll
    for (int tm = 0; tm < 4; ++tm) {
        if (tm > w) continue;
        accS[tm] = fzero;
        #pragma unroll
        for (int ks = 0; ks < 2; ++ks)
            accS[tm] = __builtin_amdgcn_mfma_f32_16x16x32_bf16(
                bfr[tm][ks], cfr[ks], accS[tm], 0, 0, 0);
    }
    __syncthreads();   // all waves done reading B before W overwrite

    // ---- build W rows i in [16w,16w+16) ----
    {
        const int i = w * 16 + a;
        const float Li = sLaF[i];
        #pragma unroll
        for (int tm = 0; tm < 4; ++tm) {
            const int d0 = i * 33 + tm * 8 + q * 2;
            if (tm > w) {
                sBW[d0] = 0; sBW[d0 + 1] = 0;
            } else {
                const float4 Ls = *(const float4*)(sLaF + tm * 16 + q * 4);
                float v[4];
                #pragma unroll
                for (int r = 0; r < 4; ++r) {
                    const int s = tm * 16 + q * 4 + r;
                    const float ww = (s <= i) ? __expf(Li - ((const float*)&Ls)[r]) : 0.f;
                    v[r] = accS[tm][r] * ww;
                }
                sBW[d0]     = pack2(v[0], v[1]);
                sBW[d0 + 1] = pack2(v[2], v[3]);
            }
        }
    }

    // ---- m4: accY = C @ h_start^T (row-tile w), scale rows by e^La_i ----
    short8 hfr[4][2];
    #pragma unroll
    for (int tp = 0; tp < 4; ++tp)
        #pragma unroll
        for (int ks = 0; ks < 2; ++ks)
            hfr[tp][ks] = frag_ld(sH, tp * 16 + a, ks * 32 + q * 8);
    floatx4 accY[4];
    #pragma unroll
    for (int tp = 0; tp < 4; ++tp) {
        accY[tp] = fzero;
        #pragma unroll
        for (int ks = 0; ks < 2; ++ks)
            accY[tp] = __builtin_amdgcn_mfma_f32_16x16x32_bf16(
                cfr[ks], hfr[tp][ks], accY[tp], 0, 0, 0);
    }
    {
        const float4 Ls = *(const float4*)(sLaF + w * 16 + q * 4);
        float e4[4];
        #pragma unroll
        for (int r = 0; r < 4; ++r) e4[r] = __expf(((const float*)&Ls)[r]);
        #pragma unroll
        for (int tp = 0; tp < 4; ++tp)
            #pragma unroll
            for (int r = 0; r < 4; ++r) accY[tp][r] *= e4[r];
    }

    // ---- m2: accY += W @ X^T (wave reads only its own W rows) ----
    short8 wfr[2], xfr[4][2];
    #pragma unroll
    for (int ks = 0; ks < 2; ++ks)
        wfr[ks] = frag_ld(sBW, w * 16 + a, ks * 32 + q * 8);
    #pragma unroll
    for (int tp = 0; tp < 4; ++tp)
        #pragma unroll
        for (int ks = 0; ks < 2; ++ks)
            xfr[tp][ks] = frag_ld(sXt, tp * 16 + a, ks * 32 + q * 8);
    #pragma unroll
    for (int tp = 0; tp < 4; ++tp)
        #pragma unroll
        for (int ks = 0; ks < 2; ++ks)
            accY[tp] = __builtin_amdgcn_mfma_f32_16x16x32_bf16(
                wfr[ks], xfr[tp][ks], accY[tp], 0, 0, 0);
    __syncthreads();   // all frag reads of sC/sXt done; safe to alias as sY

    // ---- epilogue: own-rows LDS round-trip, gate (bf16 z), bf16 store ----
    #pragma unroll
    for (int tp = 0; tp < 4; ++tp)
        #pragma unroll
        for (int r = 0; r < 4; ++r)
            sY[(w * 16 + q * 4 + r) * 66 + tp * 16 + a] = accY[tp][r];
    #pragma unroll
    for (int ii = 0; ii < 16; ++ii) {
        const int i = w * 16 + ii;
        const float y = sY[i * 66 + ln];
        const float z = bf2f(projb[(r0 + i) * PB + OFF_Z + h * 64 + ln]);
        yz[(r0 + i) * DINNER + h * 64 + ln] = f2bf(y * silu_f(z));
    }
}

// =====================================================================
extern "C" void kernel_launch(void* const* d_in, const int* in_sizes, int n_in,
                              void* d_out, int out_size, void* d_ws, size_t ws_size,
                              hipStream_t stream)
{
    const float* x       = (const float*)d_in[0];
    const float* W_in    = (const float*)d_in[1];
    const float* conv_w  = (const float*)d_in[2];
    const float* conv_b  = (const float*)d_in[3];
    const float* A_log   = (const float*)d_in[4];
    const float* dt_bias = (const float*)d_in[5];
    const float* W_out   = (const float*)d_in[6];
    float* out = (float*)d_out;

    // workspace layout (~51 MB)
    u16*   projb = (u16*)d_ws;                                  // 4096*2176 bf16
    float* dtf   = (float*)(projb + (size_t)4096 * PB);         // 4096*16 f32
    float* hl    = dtf + (size_t)4096 * 16;                     // 1024*4096 f32
    float* Pc    = hl + (size_t)1024 * 4096;                    // 1024
    float* LaBuf = Pc + 1024;                                   // 1024*64
    u16*   xbf   = (u16*)(LaBuf + 1024 * 64);                   // 4096*512 bf16
    u16*   wibf  = xbf + (size_t)4096 * DMODEL;                 // 2192*512 bf16
    u16*   wobf  = wibf + (size_t)EPROJ * DMODEL;               // 512*1024 bf16
    u16*   yzbf  = wobf + (size_t)DMODEL * DINNER;              // 4096*1024 bf16

    const int M = B_N * L_N;  // 4096
    const int n0 = M * DMODEL / 4, n1 = EPROJ * DMODEL / 4, n2 = DMODEL * DINNER / 4;

    // 0) fused casts
    cast3_kern<<<(n0 + n1 + n2 + 255) / 256, 256, 0, stream>>>(
        x, xbf, n0, W_in, wibf, n1, W_out, wobf, n2);

    // 1) in_proj: proj = x @ W_in^T  (M=4096, N=2192, K=512) -> bf16 projb + f32 dtf
    gemm_mfma_bt<128, 128, true, true><<<dim3((EPROJ + 127) / 128, M / 128), 256, 0, stream>>>(
        xbf, wibf, nullptr, projb, dtf, M, EPROJ, DMODEL);

    // 2) SSD chunked scan (MFMA, 4-wave cooperative, conv fused into p1/p3)
    ssd_phase1<<<B_N * NHEADS * NC, 256, 0, stream>>>(
        projb, dtf, conv_w, conv_b, A_log, dt_bias, hl, Pc, LaBuf);
    ssd_phase2<<<B_N * NHEADS * 16, 256, 0, stream>>>(hl, Pc);
    ssd_phase3<<<B_N * NHEADS * NC, 256, 0, stream>>>(
        projb, conv_w, conv_b, hl, LaBuf, yzbf);

    // 3) out_proj: out = yz @ W_out^T  (M=4096, N=512, K=1024), 512 blocks (2/CU)
    gemm_mfma_bt<64, 64, false, false><<<dim3(DMODEL / 64, M / 64), 256, 0, stream>>>(
        yzbf, wobf, out, nullptr, nullptr, M, DMODEL, DINNER);
}

// Round 10
// 156.061 us; speedup vs baseline: 4.3329x; 1.0034x over previous
//
#include <hip/hip_runtime.h>
#include <cstdint>
#include <cstddef>

// ---- problem constants ----
#define B_N     2
#define L_N     2048
#define DMODEL  512
#define DINNER  1024
#define DSTATE  64
#define NHEADS  16
#define EPROJ   2192      // 2*DINNER + 2*DSTATE + NHEADS
#define PB      2176      // bf16 proj row stride (z,x,B,C)
#define OFF_Z   0
#define OFF_XP  1024
#define OFF_B   2048
#define OFF_C   2112
#define LC      64        // scan chunk length (= matmul tile)
#define NC      32        // L_N / LC

typedef unsigned short u16;
typedef unsigned int   u32;
typedef __attribute__((ext_vector_type(8))) short short8;   // 8 bf16 (4 VGPRs)
typedef __attribute__((ext_vector_type(4))) float floatx4;  // MFMA acc

__device__ __forceinline__ float silu_f(float v) { return v / (1.f + __expf(-v)); }

__device__ __forceinline__ u16 f2bf(float f) {
    union { float f; uint32_t u; } v; v.f = f;
    uint32_t r = (v.u + 0x7FFFu + ((v.u >> 16) & 1u)) >> 16;  // RNE
    return (u16)r;
}

__device__ __forceinline__ float bf2f(u16 b) {
    union { u32 u; float f; } v; v.u = (u32)b << 16; return v.f;
}

__device__ __forceinline__ u32 pack2(float lo, float hi) {
    return (u32)f2bf(lo) | ((u32)f2bf(hi) << 16);
}

__device__ __forceinline__ float lane_bcast(float v, int n) {
    union { float f; uint32_t u; } a, b;
    a.f = v;
    b.u = __builtin_amdgcn_readlane(a.u, n);
    return b.f;
}

// read bf16 fragment A[row][k0..k0+7] from pair-packed LDS tile (stride 33 dwords)
__device__ __forceinline__ short8 frag_ld(const u32* s, int row, int k0) {
    const u32* q = s + row * 33 + (k0 >> 1);
    union { u32 u[4]; short8 v; } r;
    r.u[0] = q[0]; r.u[1] = q[1]; r.u[2] = q[2]; r.u[3] = q[3];
    return r.v;
}

__device__ __forceinline__ void gload_lds16(const u16* g, u16* s) {
    __builtin_amdgcn_global_load_lds(
        (const __attribute__((address_space(1))) void*)g,
        (__attribute__((address_space(3))) void*)s,
        16, 0, 0);
}

// =====================================================================
// fused fp32 -> bf16 cast for x, W_in, W_out (one launch). n's in float4 quads.
// =====================================================================
__global__ __launch_bounds__(256) void cast3_kern(
    const float* __restrict__ s0, u16* __restrict__ d0, int n0,
    const float* __restrict__ s1, u16* __restrict__ d1, int n1,
    const float* __restrict__ s2, u16* __restrict__ d2, int n2)
{
    int i = blockIdx.x * 256 + threadIdx.x;
    const float* s; u16* d;
    if (i < n0)           { s = s0; d = d0; }
    else if (i < n0 + n1) { i -= n0; s = s1; d = d1; }
    else                  { i -= n0 + n1; if (i >= n2) return; s = s2; d = d2; }
    float4 v = ((const float4*)s)[i];
    ushort4 o;
    o.x = f2bf(v.x); o.y = f2bf(v.y); o.z = f2bf(v.z); o.w = f2bf(v.w);
    ((ushort4*)d)[i] = o;
}

// =====================================================================
// bf16 MFMA GEMM (m97 pattern), generic BM/BN (BN any multiple of 32).
//   C = A[M,K] @ Bt[N,K]^T.  4 waves as 2x2; wave tile (BM/2)x(BN/2).
// Staging: 16-row groups round-robined across waves (handles BN=160).
// PSPLIT epilogue: col<2176 -> bf16 projb; 2176..2191 -> f32 dtf.
// gemm1 uses BN=160 -> 448 blocks <= 512 capacity: single scheduling
// round (576-block version had a 64-block second round = ~2x makespan).
// =====================================================================
template<int BM, int BN, bool GUARD, bool PSPLIT>
__global__ __launch_bounds__(256, 2) void gemm_mfma_bt(
    const u16* __restrict__ A, const u16* __restrict__ Bt,
    float* __restrict__ Cf, u16* __restrict__ Cb, float* __restrict__ Dt,
    int M, int N, int K)
{
    constexpr int MI = BM / 32;
    constexpr int NI = BN / 32;
    __shared__ u16 As[BM * 32];
    __shared__ u16 Bs[BN * 32];

    const int tid = threadIdx.x;
    const int w   = tid >> 6;
    const int ln  = tid & 63;
    const int wm  = w >> 1, wn = w & 1;
    const int bm  = blockIdx.y * BM;
    const int bn  = blockIdx.x * BN;

    const int srow = ln >> 2;          // 16 rows per wave-load group
    const int skq  = (ln & 3) * 8;
    const int fr = ln & 15;
    const int fq = (ln >> 4) * 8;

    floatx4 acc[MI][NI];
    const floatx4 fzero = {0.f, 0.f, 0.f, 0.f};
    #pragma unroll
    for (int mi = 0; mi < MI; ++mi)
        #pragma unroll
        for (int ni = 0; ni < NI; ++ni) acc[mi][ni] = fzero;

    for (int k0 = 0; k0 < K; k0 += 32) {
        #pragma unroll
        for (int g = 0; g < BM / 16; ++g) {
            if ((g & 3) != w) continue;        // group -> wave round-robin
            gload_lds16(A + (size_t)(bm + g * 16 + srow) * K + k0 + skq,
                        &As[g * 16 * 32]);
        }
        #pragma unroll
        for (int g = 0; g < BN / 16; ++g) {
            if ((g & 3) != w) continue;
            int rn = bn + g * 16 + srow;
            if (GUARD) rn = (rn < N) ? rn : (N - 1);
            gload_lds16(Bt + (size_t)rn * K + k0 + skq,
                        &Bs[g * 16 * 32]);
        }
        __syncthreads();

        short8 af[MI], bf[NI];
        #pragma unroll
        for (int mi = 0; mi < MI; ++mi)
            af[mi] = *(const short8*)&As[(wm * (BM / 2) + mi * 16 + fr) * 32 + fq];
        #pragma unroll
        for (int ni = 0; ni < NI; ++ni)
            bf[ni] = *(const short8*)&Bs[(wn * (BN / 2) + ni * 16 + fr) * 32 + fq];
        #pragma unroll
        for (int mi = 0; mi < MI; ++mi)
            #pragma unroll
            for (int ni = 0; ni < NI; ++ni)
                acc[mi][ni] = __builtin_amdgcn_mfma_f32_16x16x32_bf16(
                    af[mi], bf[ni], acc[mi][ni], 0, 0, 0);
        __syncthreads();
    }

    const int cr = (ln >> 4) * 4;
    const int cc = ln & 15;
    #pragma unroll
    for (int mi = 0; mi < MI; ++mi) {
        const int row0 = bm + wm * (BM / 2) + mi * 16 + cr;
        #pragma unroll
        for (int ni = 0; ni < NI; ++ni) {
            const int col = bn + wn * (BN / 2) + ni * 16 + cc;
            #pragma unroll
            for (int r = 0; r < 4; ++r) {
                const int row = row0 + r;
                const float v = acc[mi][ni][r];
                if (PSPLIT) {
                    if (col < PB)
                        Cb[(size_t)row * PB + col] = f2bf(v);
                    else if (col < EPROJ)
                        Dt[(size_t)row * 16 + (col - PB)] = v;
                } else {
                    Cf[(size_t)row * N + col] = v;
                }
            }
        }
    }
}

// =====================================================================
// SSD phase 1 — 4-wave cooperative block per (b,h,chunk), conv fused:
//   stage raw x slice (67x64 bf16) -> conv+silu during X^T pack;
//   La = cumsum(logdA);  Hc = (e^(La63-La_s) B)^T @ X  (MFMA)
// =====================================================================
__global__ __launch_bounds__(256) void ssd_phase1(
    const u16* __restrict__ projb, const float* __restrict__ dtf,
    const float* __restrict__ cw, const float* __restrict__ cb,
    const float* __restrict__ A_log, const float* __restrict__ dt_bias,
    float* __restrict__ hl, float* __restrict__ Pc, float* __restrict__ LaBuf)
{
    __shared__ u32 sBD[64 * 33];   // (e^(La63-La_s) B[s][n])^T : [n][s-pair]
    __shared__ u32 sXt[64 * 33];   // X^T: [p][s-pair]
    __shared__ u32 sXr[67 * 32];   // raw x rows r0-3..r0+63 (bf16 pairs)
    const u16* sXr16 = (const u16*)sXr;

    const int bid = blockIdx.x;               // ((b*16+h)*32 + c)
    const int c = bid & (NC - 1);
    const int h = (bid >> 5) & (NHEADS - 1);
    const int b = bid >> 9;
    const int tid = threadIdx.x;
    const int w = tid >> 6, ln = tid & 63;
    const int a = ln & 15, q = ln >> 4;
    const size_t r0 = (size_t)b * L_N + c * LC;
    const int tl0 = c * LC - 3;               // local time of LDS row 0

    // logdA + inclusive cumsum (redundant per wave; all waves identical)
    float dt = dtf[(r0 + ln) * 16 + h] + dt_bias[h];
    float sp = (dt > 15.f) ? dt : log1pf(__expf(dt));
    float La = sp * (-__expf(A_log[h]));
    #pragma unroll
    for (int d = 1; d < 64; d <<= 1) {
        float up = __shfl_up(La, d, 64);
        if (ln >= d) La += up;
    }
    if (w == 0) LaBuf[(size_t)bid * 64 + ln] = La;
    const float La63 = lane_bcast(La, 63);

    // stage raw x slice (zero-fill t<0)
    for (int idx = tid; idx < 67 * 32; idx += 256) {
        const int row = idx >> 5, c2 = idx & 31;
        u32 v = 0;
        if (tl0 + row >= 0)
            v = *(const u32*)(projb + ((size_t)b * L_N + tl0 + row) * PB + OFF_XP + h * 64 + 2 * c2);
        sXr[idx] = v;
    }
    __syncthreads();

    const int ch = h * 64 + ln;
    const float4 w4 = *(const float4*)(cw + ch * 4);
    const float bias = cb[ch];

    // staging: wave w covers s-pairs [w*8, w*8+8); conv+silu inline
    #pragma unroll
    for (int j = 0; j < 8; ++j) {
        const int sp_ = w * 8 + j, s = sp_ * 2;
        float a0 = bias, a1 = bias;
        #pragma unroll
        for (int k = 0; k < 4; ++k) {
            a0 += bf2f(sXr16[(s + k) * 64 + ln]) * ((const float*)&w4)[k];
            a1 += bf2f(sXr16[(s + 1 + k) * 64 + ln]) * ((const float*)&w4)[k];
        }
        const float x0 = silu_f(a0), x1 = silu_f(a1);
        const float w0 = __expf(La63 - lane_bcast(La, s));
        const float w1 = __expf(La63 - lane_bcast(La, s + 1));
        const float b0 = bf2f(projb[(r0 + s) * PB + OFF_B + ln]) * w0;
        const float b1 = bf2f(projb[(r0 + s + 1) * PB + OFF_B + ln]) * w1;
        sBD[ln * 33 + sp_] = pack2(b0, b1);
        sXt[ln * 33 + sp_] = pack2(x0, x1);
    }
    __syncthreads();

    // MFMA: wave w computes output tile-row tm=w (rows n in [16w,16w+16))
    short8 af[2], bf[4][2];
    #pragma unroll
    for (int ks = 0; ks < 2; ++ks)
        af[ks] = frag_ld(sBD, w * 16 + a, ks * 32 + q * 8);
    #pragma unroll
    for (int tn = 0; tn < 4; ++tn)
        #pragma unroll
        for (int ks = 0; ks < 2; ++ks)
            bf[tn][ks] = frag_ld(sXt, tn * 16 + a, ks * 32 + q * 8);

    const floatx4 fzero = {0.f, 0.f, 0.f, 0.f};
    floatx4 acc[4];
    #pragma unroll
    for (int tn = 0; tn < 4; ++tn) {
        acc[tn] = fzero;
        #pragma unroll
        for (int ks = 0; ks < 2; ++ks)
            acc[tn] = __builtin_amdgcn_mfma_f32_16x16x32_bf16(
                af[ks], bf[tn][ks], acc[tn], 0, 0, 0);
    }

    float* hp = hl + (size_t)bid * (DSTATE * 64);
    #pragma unroll
    for (int tn = 0; tn < 4; ++tn)
        #pragma unroll
        for (int r = 0; r < 4; ++r)
            hp[(w * 16 + q * 4 + r) * 64 + tn * 16 + a] = acc[tn][r];
    if (tid == 0) Pc[bid] = __expf(La63);
}

// =====================================================================
// SSD phase 2 — element-parallel inter-chunk carry, in place over hl.
// All 32 chunk loads independent: batch-issue, scan in regs, store.
// =====================================================================
__global__ __launch_bounds__(256) void ssd_phase2(
    float* __restrict__ hl, const float* __restrict__ Pc)
{
    const int bid = blockIdx.x;               // bh*16 + eg
    const int bh = bid >> 4;
    const int e = (bid & 15) * 256 + threadIdx.x;   // state element 0..4095
    const size_t base = (size_t)(bh * NC) * 4096 + e;

    float v[NC];
    #pragma unroll
    for (int c = 0; c < NC; ++c)
        v[c] = hl[base + (size_t)c * 4096];

    float carry = 0.f;
    #pragma unroll
    for (int c = 0; c < NC; ++c) {
        const float cur = v[c];
        v[c] = carry;                          // h_start entering chunk c
        carry = fmaf(Pc[bh * NC + c], carry, cur);
    }

    #pragma unroll
    for (int c = 0; c < NC; ++c)
        hl[base + (size_t)c * 4096] = v[c];
}

// =====================================================================
// SSD phase 3 — 4-wave cooperative block per (b,h,chunk), conv fused:
//   S^T = B @ C;  W[i][s] = S[i,s] e^(La_i-La_s) (s<=i)
//   Y = diag(e^La) C @ h_start^T + W @ X^T;  yz = Y * silu(z)
// =====================================================================
__global__ __launch_bounds__(256) void ssd_phase3(
    const u16* __restrict__ projb,
    const float* __restrict__ cw, const float* __restrict__ cb,
    const float* __restrict__ hl, const float* __restrict__ LaBuf,
    u16* __restrict__ yz)
{
    __shared__ char lds[42624];
    u32* sBW   = (u32*)lds;              // B natural, then W (aliased)
    u32* sC    = (u32*)(lds + 8448);     // C natural [i][n-pair]
    u32* sXt   = (u32*)(lds + 16896);    // X^T [p][s-pair]
    u32* sH    = (u32*)(lds + 25344);    // h_start^T [p][n-pair]
    float* sLaF = (float*)(lds + 33792); // La[64]
    u32* sXr   = (u32*)(lds + 34048);    // raw x rows r0-3..r0+63
    float* sY  = (float*)(lds + 8448);   // f32 [i][p] 64x66, aliases sC+sXt (epilogue)
    const u16* sXr16 = (const u16*)sXr;

    const int bid = blockIdx.x;
    const int c = bid & (NC - 1);
    const int h = (bid >> 5) & (NHEADS - 1);
    const int b = bid >> 9;
    const int tid = threadIdx.x;
    const int w = tid >> 6, ln = tid & 63;
    const int a = ln & 15, q = ln >> 4;
    const int hw = ln >> 5, k32 = ln & 31;
    const size_t r0 = (size_t)b * L_N + c * LC;
    const int tl0 = c * LC - 3;

    if (tid < 64) sLaF[tid] = LaBuf[(size_t)bid * 64 + tid];

    // stage raw x slice
    for (int idx = tid; idx < 67 * 32; idx += 256) {
        const int row = idx >> 5, c2 = idx & 31;
        u32 v = 0;
        if (tl0 + row >= 0)
            v = *(const u32*)(projb + ((size_t)b * L_N + tl0 + row) * PB + OFF_XP + h * 64 + 2 * c2);
        sXr[idx] = v;
    }
    __syncthreads();

    const int ch = h * 64 + ln;
    const float4 w4 = *(const float4*)(cw + ch * 4);
    const float bias = cb[ch];

    // stage B, C natural (raw bf16-pair copies); X^T (conv inline), H^T pack
    const float* hs = hl + (size_t)bid * 4096;
    #pragma unroll
    for (int j = 0; j < 8; ++j) {
        const int rp = w * 8 + j;
        const int row = rp * 2 + hw;
        sBW[row * 33 + k32] = *(const u32*)(projb + (r0 + row) * PB + OFF_B + 2 * k32);
        sC [row * 33 + k32] = *(const u32*)(projb + (r0 + row) * PB + OFF_C + 2 * k32);

        const int s = rp * 2;
        float a0 = bias, a1 = bias;
        #pragma unroll
        for (int k = 0; k < 4; ++k) {
            a0 += bf2f(sXr16[(s + k) * 64 + ln]) * ((const float*)&w4)[k];
            a1 += bf2f(sXr16[(s + 1 + k) * 64 + ln]) * ((const float*)&w4)[k];
        }
        sXt[ln * 33 + rp] = pack2(silu_f(a0), silu_f(a1));

        sH[ln * 33 + rp] = pack2(hs[(2 * rp) * 64 + ln], hs[(2 * rp + 1) * 64 + ln]);
    }
    __syncthreads();

    const floatx4 fzero = {0.f, 0.f, 0.f, 0.f};

    // ---- m1: S^T tiles [tm][tn=w], tm<=w ----
    short8 cfr[2], bfr[4][2];
    #pragma unroll
    for (int ks = 0; ks < 2; ++ks)
        cfr[ks] = frag_ld(sC, w * 16 + a, ks * 32 + q * 8);
    #pragma unroll
    for (int tm = 0; tm < 4; ++tm)
        if (tm <= w)
            #pragma unroll
            for (int ks = 0; ks < 2; ++ks)
                bfr[tm][ks] = frag_ld(sBW, tm * 16 + a, ks * 32 + q * 8);
    floatx4 accS[4];
    #pragma unroll
    for (int tm = 0; tm < 4; ++tm) {
        if (tm > w) continue;
        accS[tm] = fzero;
        #pragma unroll
        for (int ks = 0; ks < 2; ++ks)
            accS[tm] = __builtin_amdgcn_mfma_f32_16x16x32_bf16(
                bfr[tm][ks], cfr[ks], accS[tm], 0, 0, 0);
    }
    __syncthreads();   // all waves done reading B before W overwrite

    // ---- build W rows i in [16w,16w+16) ----
    {
        const int i = w * 16 + a;
        const float Li = sLaF[i];
        #pragma unroll
        for (int tm = 0; tm < 4; ++tm) {
            const int d0 = i * 33 + tm * 8 + q * 2;
            if (tm > w) {
                sBW[d0] = 0; sBW[d0 + 1] = 0;
            } else {
                const float4 Ls = *(const float4*)(sLaF + tm * 16 + q * 4);
                float v[4];
                #pragma unroll
                for (int r = 0; r < 4; ++r) {
                    const int s = tm * 16 + q * 4 + r;
                    const float ww = (s <= i) ? __expf(Li - ((const float*)&Ls)[r]) : 0.f;
                    v[r] = accS[tm][r] * ww;
                }
                sBW[d0]     = pack2(v[0], v[1]);
                sBW[d0 + 1] = pack2(v[2], v[3]);
            }
        }
    }

    // ---- m4: accY = C @ h_start^T (row-tile w), scale rows by e^La_i ----
    short8 hfr[4][2];
    #pragma unroll
    for (int tp = 0; tp < 4; ++tp)
        #pragma unroll
        for (int ks = 0; ks < 2; ++ks)
            hfr[tp][ks] = frag_ld(sH, tp * 16 + a, ks * 32 + q * 8);
    floatx4 accY[4];
    #pragma unroll
    for (int tp = 0; tp < 4; ++tp) {
        accY[tp] = fzero;
        #pragma unroll
        for (int ks = 0; ks < 2; ++ks)
            accY[tp] = __builtin_amdgcn_mfma_f32_16x16x32_bf16(
                cfr[ks], hfr[tp][ks], accY[tp], 0, 0, 0);
    }
    {
        const float4 Ls = *(const float4*)(sLaF + w * 16 + q * 4);
        float e4[4];
        #pragma unroll
        for (int r = 0; r < 4; ++r) e4[r] = __expf(((const float*)&Ls)[r]);
        #pragma unroll
        for (int tp = 0; tp < 4; ++tp)
            #pragma unroll
            for (int r = 0; r < 4; ++r) accY[tp][r] *= e4[r];
    }

    // ---- m2: accY += W @ X^T (wave reads only its own W rows) ----
    short8 wfr[2], xfr[4][2];
    #pragma unroll
    for (int ks = 0; ks < 2; ++ks)
        wfr[ks] = frag_ld(sBW, w * 16 + a, ks * 32 + q * 8);
    #pragma unroll
    for (int tp = 0; tp < 4; ++tp)
        #pragma unroll
        for (int ks = 0; ks < 2; ++ks)
            xfr[tp][ks] = frag_ld(sXt, tp * 16 + a, ks * 32 + q * 8);
    #pragma unroll
    for (int tp = 0; tp < 4; ++tp)
        #pragma unroll
        for (int ks = 0; ks < 2; ++ks)
            accY[tp] = __builtin_amdgcn_mfma_f32_16x16x32_bf16(
                wfr[ks], xfr[tp][ks], accY[tp], 0, 0, 0);
    __syncthreads();   // all frag reads of sC/sXt done; safe to alias as sY

    // ---- epilogue: own-rows LDS round-trip, gate (bf16 z), bf16 store ----
    #pragma unroll
    for (int tp = 0; tp < 4; ++tp)
        #pragma unroll
        for (int r = 0; r < 4; ++r)
            sY[(w * 16 + q * 4 + r) * 66 + tp * 16 + a] = accY[tp][r];
    #pragma unroll
    for (int ii = 0; ii < 16; ++ii) {
        const int i = w * 16 + ii;
        const float y = sY[i * 66 + ln];
        const float z = bf2f(projb[(r0 + i) * PB + OFF_Z + h * 64 + ln]);
        yz[(r0 + i) * DINNER + h * 64 + ln] = f2bf(y * silu_f(z));
    }
}

// =====================================================================
extern "C" void kernel_launch(void* const* d_in, const int* in_sizes, int n_in,
                              void* d_out, int out_size, void* d_ws, size_t ws_size,
                              hipStream_t stream)
{
    const float* x       = (const float*)d_in[0];
    const float* W_in    = (const float*)d_in[1];
    const float* conv_w  = (const float*)d_in[2];
    const float* conv_b  = (const float*)d_in[3];
    const float* A_log   = (const float*)d_in[4];
    const float* dt_bias = (const float*)d_in[5];
    const float* W_out   = (const float*)d_in[6];
    float* out = (float*)d_out;

    // workspace layout (~51 MB)
    u16*   projb = (u16*)d_ws;                                  // 4096*2176 bf16
    float* dtf   = (float*)(projb + (size_t)4096 * PB);         // 4096*16 f32
    float* hl    = dtf + (size_t)4096 * 16;                     // 1024*4096 f32
    float* Pc    = hl + (size_t)1024 * 4096;                    // 1024
    float* LaBuf = Pc + 1024;                                   // 1024*64
    u16*   xbf   = (u16*)(LaBuf + 1024 * 64);                   // 4096*512 bf16
    u16*   wibf  = xbf + (size_t)4096 * DMODEL;                 // 2192*512 bf16
    u16*   wobf  = wibf + (size_t)EPROJ * DMODEL;               // 512*1024 bf16
    u16*   yzbf  = wobf + (size_t)DMODEL * DINNER;              // 4096*1024 bf16

    const int M = B_N * L_N;  // 4096
    const int n0 = M * DMODEL / 4, n1 = EPROJ * DMODEL / 4, n2 = DMODEL * DINNER / 4;

    // 0) fused casts
    cast3_kern<<<(n0 + n1 + n2 + 255) / 256, 256, 0, stream>>>(
        x, xbf, n0, W_in, wibf, n1, W_out, wobf, n2);

    // 1) in_proj: proj = x @ W_in^T (M=4096, N=2192, K=512)
    //    BN=160 -> 14x32 = 448 blocks (single occupancy round at 2/CU)
    gemm_mfma_bt<128, 160, true, true><<<dim3(14, M / 128), 256, 0, stream>>>(
        xbf, wibf, nullptr, projb, dtf, M, EPROJ, DMODEL);

    // 2) SSD chunked scan (MFMA, 4-wave cooperative, conv fused into p1/p3)
    ssd_phase1<<<B_N * NHEADS * NC, 256, 0, stream>>>(
        projb, dtf, conv_w, conv_b, A_log, dt_bias, hl, Pc, LaBuf);
    ssd_phase2<<<B_N * NHEADS * 16, 256, 0, stream>>>(hl, Pc);
    ssd_phase3<<<B_N * NHEADS * NC, 256, 0, stream>>>(
        projb, conv_w, conv_b, hl, LaBuf, yzbf);

    // 3) out_proj: out = yz @ W_out^T  (M=4096, N=512, K=1024), 512 blocks (2/CU)
    gemm_mfma_bt<64, 64, false, false><<<dim3(DMODEL / 64, M / 64), 256, 0, stream>>>(
        yzbf, wobf, out, nullptr, nullptr, M, DMODEL, DINNER);
}

// Round 11
// 149.560 us; speedup vs baseline: 4.5213x; 1.0435x over previous
//
#include <hip/hip_runtime.h>
#include <cstdint>
#include <cstddef>

// ---- problem constants ----
#define B_N     2
#define L_N     2048
#define DMODEL  512
#define DINNER  1024
#define DSTATE  64
#define NHEADS  16
#define EPROJ   2192      // 2*DINNER + 2*DSTATE + NHEADS
#define PB      2176      // bf16 proj row stride (z,x,B,C)
#define OFF_Z   0
#define OFF_XP  1024
#define OFF_B   2048
#define OFF_C   2112
#define LC      64        // scan chunk length (= matmul tile)
#define NC      32        // L_N / LC

typedef unsigned short u16;
typedef unsigned int   u32;
typedef __attribute__((ext_vector_type(8))) short short8;   // 8 bf16 (4 VGPRs)
typedef __attribute__((ext_vector_type(4))) float floatx4;  // MFMA acc

__device__ __forceinline__ float silu_f(float v) { return v / (1.f + __expf(-v)); }

__device__ __forceinline__ u16 f2bf(float f) {
    union { float f; uint32_t u; } v; v.f = f;
    uint32_t r = (v.u + 0x7FFFu + ((v.u >> 16) & 1u)) >> 16;  // RNE
    return (u16)r;
}

__device__ __forceinline__ float bf2f(u16 b) {
    union { u32 u; float f; } v; v.u = (u32)b << 16; return v.f;
}

__device__ __forceinline__ u32 pack2(float lo, float hi) {
    return (u32)f2bf(lo) | ((u32)f2bf(hi) << 16);
}

__device__ __forceinline__ float lane_bcast(float v, int n) {
    union { float f; uint32_t u; } a, b;
    a.f = v;
    b.u = __builtin_amdgcn_readlane(a.u, n);
    return b.f;
}

// read bf16 fragment A[row][k0..k0+7] from pair-packed LDS tile (stride 33 dwords)
__device__ __forceinline__ short8 frag_ld(const u32* s, int row, int k0) {
    const u32* q = s + row * 33 + (k0 >> 1);
    union { u32 u[4]; short8 v; } r;
    r.u[0] = q[0]; r.u[1] = q[1]; r.u[2] = q[2]; r.u[3] = q[3];
    return r.v;
}

__device__ __forceinline__ void gload_lds16(const u16* g, u16* s) {
    __builtin_amdgcn_global_load_lds(
        (const __attribute__((address_space(1))) void*)g,
        (__attribute__((address_space(3))) void*)s,
        16, 0, 0);
}

// =====================================================================
// fused fp32 -> bf16 cast for x, W_in, W_out (one launch). n's in float4 quads.
// =====================================================================
__global__ __launch_bounds__(256) void cast3_kern(
    const float* __restrict__ s0, u16* __restrict__ d0, int n0,
    const float* __restrict__ s1, u16* __restrict__ d1, int n1,
    const float* __restrict__ s2, u16* __restrict__ d2, int n2)
{
    int i = blockIdx.x * 256 + threadIdx.x;
    const float* s; u16* d;
    if (i < n0)           { s = s0; d = d0; }
    else if (i < n0 + n1) { i -= n0; s = s1; d = d1; }
    else                  { i -= n0 + n1; if (i >= n2) return; s = s2; d = d2; }
    float4 v = ((const float4*)s)[i];
    ushort4 o;
    o.x = f2bf(v.x); o.y = f2bf(v.y); o.z = f2bf(v.z); o.w = f2bf(v.w);
    ((ushort4*)d)[i] = o;
}

// =====================================================================
// bf16 MFMA GEMM (m97 pattern), generic BM/BN (BN any multiple of 32).
//   C = A[M,K] @ Bt[N,K]^T.  4 waves as 2x2; wave tile (BM/2)x(BN/2).
// Staging: 16-row groups round-robined across waves (handles BN=160).
// PSPLIT epilogue: col<2176 -> bf16 projb; 2176..2191 -> f32 dtf.
// =====================================================================
template<int BM, int BN, bool GUARD, bool PSPLIT>
__global__ __launch_bounds__(256, 2) void gemm_mfma_bt(
    const u16* __restrict__ A, const u16* __restrict__ Bt,
    float* __restrict__ Cf, u16* __restrict__ Cb, float* __restrict__ Dt,
    int M, int N, int K)
{
    constexpr int MI = BM / 32;
    constexpr int NI = BN / 32;
    __shared__ u16 As[BM * 32];
    __shared__ u16 Bs[BN * 32];

    const int tid = threadIdx.x;
    const int w   = tid >> 6;
    const int ln  = tid & 63;
    const int wm  = w >> 1, wn = w & 1;
    const int bm  = blockIdx.y * BM;
    const int bn  = blockIdx.x * BN;

    const int srow = ln >> 2;          // 16 rows per wave-load group
    const int skq  = (ln & 3) * 8;
    const int fr = ln & 15;
    const int fq = (ln >> 4) * 8;

    floatx4 acc[MI][NI];
    const floatx4 fzero = {0.f, 0.f, 0.f, 0.f};
    #pragma unroll
    for (int mi = 0; mi < MI; ++mi)
        #pragma unroll
        for (int ni = 0; ni < NI; ++ni) acc[mi][ni] = fzero;

    for (int k0 = 0; k0 < K; k0 += 32) {
        #pragma unroll
        for (int g = 0; g < BM / 16; ++g) {
            if ((g & 3) != w) continue;        // group -> wave round-robin
            gload_lds16(A + (size_t)(bm + g * 16 + srow) * K + k0 + skq,
                        &As[g * 16 * 32]);
        }
        #pragma unroll
        for (int g = 0; g < BN / 16; ++g) {
            if ((g & 3) != w) continue;
            int rn = bn + g * 16 + srow;
            if (GUARD) rn = (rn < N) ? rn : (N - 1);
            gload_lds16(Bt + (size_t)rn * K + k0 + skq,
                        &Bs[g * 16 * 32]);
        }
        __syncthreads();

        short8 af[MI], bf[NI];
        #pragma unroll
        for (int mi = 0; mi < MI; ++mi)
            af[mi] = *(const short8*)&As[(wm * (BM / 2) + mi * 16 + fr) * 32 + fq];
        #pragma unroll
        for (int ni = 0; ni < NI; ++ni)
            bf[ni] = *(const short8*)&Bs[(wn * (BN / 2) + ni * 16 + fr) * 32 + fq];
        #pragma unroll
        for (int mi = 0; mi < MI; ++mi)
            #pragma unroll
            for (int ni = 0; ni < NI; ++ni)
                acc[mi][ni] = __builtin_amdgcn_mfma_f32_16x16x32_bf16(
                    af[mi], bf[ni], acc[mi][ni], 0, 0, 0);
        __syncthreads();
    }

    const int cr = (ln >> 4) * 4;
    const int cc = ln & 15;
    #pragma unroll
    for (int mi = 0; mi < MI; ++mi) {
        const int row0 = bm + wm * (BM / 2) + mi * 16 + cr;
        #pragma unroll
        for (int ni = 0; ni < NI; ++ni) {
            const int col = bn + wn * (BN / 2) + ni * 16 + cc;
            #pragma unroll
            for (int r = 0; r < 4; ++r) {
                const int row = row0 + r;
                const float v = acc[mi][ni][r];
                if (PSPLIT) {
                    if (col < PB)
                        Cb[(size_t)row * PB + col] = f2bf(v);
                    else if (col < EPROJ)
                        Dt[(size_t)row * 16 + (col - PB)] = v;
                } else {
                    Cf[(size_t)row * N + col] = v;
                }
            }
        }
    }
}

// =====================================================================
// SSD phase 1 — 4-wave cooperative block per (b,h,chunk), conv fused:
//   stage raw x slice (67x64 bf16) -> conv+silu during X^T pack;
//   La = cumsum(logdA);  Hc = (e^(La63-La_s) B)^T @ X  (MFMA)
//   NEW: exports the conv'd X^T tile (bf16-pair, [sp][ln] coalesced) so
//   phase3 doesn't redo the slab staging + conv (was ~128 ds_read_u16).
// =====================================================================
__global__ __launch_bounds__(256) void ssd_phase1(
    const u16* __restrict__ projb, const float* __restrict__ dtf,
    const float* __restrict__ cw, const float* __restrict__ cb,
    const float* __restrict__ A_log, const float* __restrict__ dt_bias,
    float* __restrict__ hl, float* __restrict__ Pc, float* __restrict__ LaBuf,
    u32* __restrict__ xT)
{
    __shared__ u32 sBD[64 * 33];   // (e^(La63-La_s) B[s][n])^T : [n][s-pair]
    __shared__ u32 sXt[64 * 33];   // X^T: [p][s-pair]
    __shared__ u32 sXr[67 * 32];   // raw x rows r0-3..r0+63 (bf16 pairs)
    const u16* sXr16 = (const u16*)sXr;

    const int bid = blockIdx.x;               // ((b*16+h)*32 + c)
    const int c = bid & (NC - 1);
    const int h = (bid >> 5) & (NHEADS - 1);
    const int b = bid >> 9;
    const int tid = threadIdx.x;
    const int w = tid >> 6, ln = tid & 63;
    const int a = ln & 15, q = ln >> 4;
    const size_t r0 = (size_t)b * L_N + c * LC;
    const int tl0 = c * LC - 3;               // local time of LDS row 0

    // logdA + inclusive cumsum (redundant per wave; all waves identical)
    float dt = dtf[(r0 + ln) * 16 + h] + dt_bias[h];
    float sp = (dt > 15.f) ? dt : log1pf(__expf(dt));
    float La = sp * (-__expf(A_log[h]));
    #pragma unroll
    for (int d = 1; d < 64; d <<= 1) {
        float up = __shfl_up(La, d, 64);
        if (ln >= d) La += up;
    }
    if (w == 0) LaBuf[(size_t)bid * 64 + ln] = La;
    const float La63 = lane_bcast(La, 63);

    // stage raw x slice (zero-fill t<0)
    for (int idx = tid; idx < 67 * 32; idx += 256) {
        const int row = idx >> 5, c2 = idx & 31;
        u32 v = 0;
        if (tl0 + row >= 0)
            v = *(const u32*)(projb + ((size_t)b * L_N + tl0 + row) * PB + OFF_XP + h * 64 + 2 * c2);
        sXr[idx] = v;
    }
    __syncthreads();

    const int ch = h * 64 + ln;
    const float4 w4 = *(const float4*)(cw + ch * 4);
    const float bias = cb[ch];

    // staging: wave w covers s-pairs [w*8, w*8+8); conv+silu inline
    #pragma unroll
    for (int j = 0; j < 8; ++j) {
        const int sp_ = w * 8 + j, s = sp_ * 2;
        float a0 = bias, a1 = bias;
        #pragma unroll
        for (int k = 0; k < 4; ++k) {
            a0 += bf2f(sXr16[(s + k) * 64 + ln]) * ((const float*)&w4)[k];
            a1 += bf2f(sXr16[(s + 1 + k) * 64 + ln]) * ((const float*)&w4)[k];
        }
        const float x0 = silu_f(a0), x1 = silu_f(a1);
        const u32 xp = pack2(x0, x1);
        sXt[ln * 33 + sp_] = xp;
        xT[(size_t)bid * 2048 + sp_ * 64 + ln] = xp;   // export for phase3
        const float w0 = __expf(La63 - lane_bcast(La, s));
        const float w1 = __expf(La63 - lane_bcast(La, s + 1));
        const float b0 = bf2f(projb[(r0 + s) * PB + OFF_B + ln]) * w0;
        const float b1 = bf2f(projb[(r0 + s + 1) * PB + OFF_B + ln]) * w1;
        sBD[ln * 33 + sp_] = pack2(b0, b1);
    }
    __syncthreads();

    // MFMA: wave w computes output tile-row tm=w (rows n in [16w,16w+16))
    short8 af[2], bf[4][2];
    #pragma unroll
    for (int ks = 0; ks < 2; ++ks)
        af[ks] = frag_ld(sBD, w * 16 + a, ks * 32 + q * 8);
    #pragma unroll
    for (int tn = 0; tn < 4; ++tn)
        #pragma unroll
        for (int ks = 0; ks < 2; ++ks)
            bf[tn][ks] = frag_ld(sXt, tn * 16 + a, ks * 32 + q * 8);

    const floatx4 fzero = {0.f, 0.f, 0.f, 0.f};
    floatx4 acc[4];
    #pragma unroll
    for (int tn = 0; tn < 4; ++tn) {
        acc[tn] = fzero;
        #pragma unroll
        for (int ks = 0; ks < 2; ++ks)
            acc[tn] = __builtin_amdgcn_mfma_f32_16x16x32_bf16(
                af[ks], bf[tn][ks], acc[tn], 0, 0, 0);
    }

    float* hp = hl + (size_t)bid * (DSTATE * 64);
    #pragma unroll
    for (int tn = 0; tn < 4; ++tn)
        #pragma unroll
        for (int r = 0; r < 4; ++r)
            hp[(w * 16 + q * 4 + r) * 64 + tn * 16 + a] = acc[tn][r];
    if (tid == 0) Pc[bid] = __expf(La63);
}

// =====================================================================
// SSD phase 2 — element-parallel inter-chunk carry, in place over hl.
// =====================================================================
__global__ __launch_bounds__(256) void ssd_phase2(
    float* __restrict__ hl, const float* __restrict__ Pc)
{
    const int bid = blockIdx.x;               // bh*16 + eg
    const int bh = bid >> 4;
    const int e = (bid & 15) * 256 + threadIdx.x;   // state element 0..4095
    const size_t base = (size_t)(bh * NC) * 4096 + e;

    float v[NC];
    #pragma unroll
    for (int c = 0; c < NC; ++c)
        v[c] = hl[base + (size_t)c * 4096];

    float carry = 0.f;
    #pragma unroll
    for (int c = 0; c < NC; ++c) {
        const float cur = v[c];
        v[c] = carry;                          // h_start entering chunk c
        carry = fmaf(Pc[bh * NC + c], carry, cur);
    }

    #pragma unroll
    for (int c = 0; c < NC; ++c)
        hl[base + (size_t)c * 4096] = v[c];
}

// =====================================================================
// SSD phase 3 — 4-wave cooperative block per (b,h,chunk):
//   X^T comes precomputed from phase1 (straight coalesced copy);
//   S^T = B @ C;  W[i][s] = S[i,s] e^(La_i-La_s) (s<=i)
//   Y = diag(e^La) C @ h_start^T + W @ X^T;  yz = Y * silu(z)
// =====================================================================
__global__ __launch_bounds__(256) void ssd_phase3(
    const u16* __restrict__ projb, const u32* __restrict__ xT,
    const float* __restrict__ hl, const float* __restrict__ LaBuf,
    u16* __restrict__ yz)
{
    __shared__ char lds[34048];
    u32* sBW   = (u32*)lds;              // B natural, then W (aliased)
    u32* sC    = (u32*)(lds + 8448);     // C natural [i][n-pair]
    u32* sXt   = (u32*)(lds + 16896);    // X^T [p][s-pair]
    u32* sH    = (u32*)(lds + 25344);    // h_start^T [p][n-pair]
    float* sLaF = (float*)(lds + 33792); // La[64]
    float* sY  = (float*)(lds + 8448);   // f32 [i][p] 64x66, aliases sC+sXt (epilogue)

    const int bid = blockIdx.x;
    const int c = bid & (NC - 1);
    const int h = (bid >> 5) & (NHEADS - 1);
    const int b = bid >> 9;
    const int tid = threadIdx.x;
    const int w = tid >> 6, ln = tid & 63;
    const int a = ln & 15, q = ln >> 4;
    const int hw = ln >> 5, k32 = ln & 31;
    const size_t r0 = (size_t)b * L_N + c * LC;

    if (tid < 64) sLaF[tid] = LaBuf[(size_t)bid * 64 + tid];

    // single staging pass: B, C natural (raw copies); X^T copy; H^T pack
    const float* hs = hl + (size_t)bid * 4096;
    #pragma unroll
    for (int j = 0; j < 8; ++j) {
        const int rp = w * 8 + j;
        const int row = rp * 2 + hw;
        sBW[row * 33 + k32] = *(const u32*)(projb + (r0 + row) * PB + OFF_B + 2 * k32);
        sC [row * 33 + k32] = *(const u32*)(projb + (r0 + row) * PB + OFF_C + 2 * k32);
        sXt[ln * 33 + rp] = xT[(size_t)bid * 2048 + rp * 64 + ln];
        sH [ln * 33 + rp] = pack2(hs[(2 * rp) * 64 + ln], hs[(2 * rp + 1) * 64 + ln]);
    }
    __syncthreads();

    const floatx4 fzero = {0.f, 0.f, 0.f, 0.f};

    // ---- m1: S^T tiles [tm][tn=w], tm<=w ----
    short8 cfr[2], bfr[4][2];
    #pragma unroll
    for (int ks = 0; ks < 2; ++ks)
        cfr[ks] = frag_ld(sC, w * 16 + a, ks * 32 + q * 8);
    #pragma unroll
    for (int tm = 0; tm < 4; ++tm)
        if (tm <= w)
            #pragma unroll
            for (int ks = 0; ks < 2; ++ks)
                bfr[tm][ks] = frag_ld(sBW, tm * 16 + a, ks * 32 + q * 8);
    floatx4 accS[4];
    #pragma unroll
    for (int tm = 0; tm < 4; ++tm) {
        if (tm > w) continue;
        accS[tm] = fzero;
        #pragma unroll
        for (int ks = 0; ks < 2; ++ks)
            accS[tm] = __builtin_amdgcn_mfma_f32_16x16x32_bf16(
                bfr[tm][ks], cfr[ks], accS[tm], 0, 0, 0);
    }
    __syncthreads();   // all waves done reading B before W overwrite

    // ---- build W rows i in [16w,16w+16) ----
    {
        const int i = w * 16 + a;
        const float Li = sLaF[i];
        #pragma unroll
        for (int tm = 0; tm < 4; ++tm) {
            const int d0 = i * 33 + tm * 8 + q * 2;
            if (tm > w) {
                sBW[d0] = 0; sBW[d0 + 1] = 0;
            } else {
                const float4 Ls = *(const float4*)(sLaF + tm * 16 + q * 4);
                float v[4];
                #pragma unroll
                for (int r = 0; r < 4; ++r) {
                    const int s = tm * 16 + q * 4 + r;
                    const float ww = (s <= i) ? __expf(Li - ((const float*)&Ls)[r]) : 0.f;
                    v[r] = accS[tm][r] * ww;
                }
                sBW[d0]     = pack2(v[0], v[1]);
                sBW[d0 + 1] = pack2(v[2], v[3]);
            }
        }
    }

    // ---- m4: accY = C @ h_start^T (row-tile w), scale rows by e^La_i ----
    short8 hfr[4][2];
    #pragma unroll
    for (int tp = 0; tp < 4; ++tp)
        #pragma unroll
        for (int ks = 0; ks < 2; ++ks)
            hfr[tp][ks] = frag_ld(sH, tp * 16 + a, ks * 32 + q * 8);
    floatx4 accY[4];
    #pragma unroll
    for (int tp = 0; tp < 4; ++tp) {
        accY[tp] = fzero;
        #pragma unroll
        for (int ks = 0; ks < 2; ++ks)
            accY[tp] = __builtin_amdgcn_mfma_f32_16x16x32_bf16(
                cfr[ks], hfr[tp][ks], accY[tp], 0, 0, 0);
    }
    {
        const float4 Ls = *(const float4*)(sLaF + w * 16 + q * 4);
        float e4[4];
        #pragma unroll
        for (int r = 0; r < 4; ++r) e4[r] = __expf(((const float*)&Ls)[r]);
        #pragma unroll
        for (int tp = 0; tp < 4; ++tp)
            #pragma unroll
            for (int r = 0; r < 4; ++r) accY[tp][r] *= e4[r];
    }

    // ---- m2: accY += W @ X^T (wave reads only its own W rows) ----
    short8 wfr[2], xfr[4][2];
    #pragma unroll
    for (int ks = 0; ks < 2; ++ks)
        wfr[ks] = frag_ld(sBW, w * 16 + a, ks * 32 + q * 8);
    #pragma unroll
    for (int tp = 0; tp < 4; ++tp)
        #pragma unroll
        for (int ks = 0; ks < 2; ++ks)
            xfr[tp][ks] = frag_ld(sXt, tp * 16 + a, ks * 32 + q * 8);
    #pragma unroll
    for (int tp = 0; tp < 4; ++tp)
        #pragma unroll
        for (int ks = 0; ks < 2; ++ks)
            accY[tp] = __builtin_amdgcn_mfma_f32_16x16x32_bf16(
                wfr[ks], xfr[tp][ks], accY[tp], 0, 0, 0);
    __syncthreads();   // all frag reads of sC/sXt done; safe to alias as sY

    // ---- epilogue: own-rows LDS round-trip, gate (bf16 z), bf16 store ----
    #pragma unroll
    for (int tp = 0; tp < 4; ++tp)
        #pragma unroll
        for (int r = 0; r < 4; ++r)
            sY[(w * 16 + q * 4 + r) * 66 + tp * 16 + a] = accY[tp][r];
    #pragma unroll
    for (int ii = 0; ii < 16; ++ii) {
        const int i = w * 16 + ii;
        const float y = sY[i * 66 + ln];
        const float z = bf2f(projb[(r0 + i) * PB + OFF_Z + h * 64 + ln]);
        yz[(r0 + i) * DINNER + h * 64 + ln] = f2bf(y * silu_f(z));
    }
}

// =====================================================================
extern "C" void kernel_launch(void* const* d_in, const int* in_sizes, int n_in,
                              void* d_out, int out_size, void* d_ws, size_t ws_size,
                              hipStream_t stream)
{
    const float* x       = (const float*)d_in[0];
    const float* W_in    = (const float*)d_in[1];
    const float* conv_w  = (const float*)d_in[2];
    const float* conv_b  = (const float*)d_in[3];
    const float* A_log   = (const float*)d_in[4];
    const float* dt_bias = (const float*)d_in[5];
    const float* W_out   = (const float*)d_in[6];
    float* out = (float*)d_out;

    // workspace layout (~59 MB)
    u16*   projb = (u16*)d_ws;                                  // 4096*2176 bf16
    float* dtf   = (float*)(projb + (size_t)4096 * PB);         // 4096*16 f32
    float* hl    = dtf + (size_t)4096 * 16;                     // 1024*4096 f32
    float* Pc    = hl + (size_t)1024 * 4096;                    // 1024
    float* LaBuf = Pc + 1024;                                   // 1024*64
    u16*   xbf   = (u16*)(LaBuf + 1024 * 64);                   // 4096*512 bf16
    u16*   wibf  = xbf + (size_t)4096 * DMODEL;                 // 2192*512 bf16
    u16*   wobf  = wibf + (size_t)EPROJ * DMODEL;               // 512*1024 bf16
    u16*   yzbf  = wobf + (size_t)DMODEL * DINNER;              // 4096*1024 bf16
    u32*   xT    = (u32*)(yzbf + (size_t)4096 * DINNER);        // 1024*2048 u32 (conv'd X^T)

    const int M = B_N * L_N;  // 4096
    const int n0 = M * DMODEL / 4, n1 = EPROJ * DMODEL / 4, n2 = DMODEL * DINNER / 4;

    // 0) fused casts
    cast3_kern<<<(n0 + n1 + n2 + 255) / 256, 256, 0, stream>>>(
        x, xbf, n0, W_in, wibf, n1, W_out, wobf, n2);

    // 1) in_proj: proj = x @ W_in^T (M=4096, N=2192, K=512), BN=160 -> 448 blocks
    gemm_mfma_bt<128, 160, true, true><<<dim3(14, M / 128), 256, 0, stream>>>(
        xbf, wibf, nullptr, projb, dtf, M, EPROJ, DMODEL);

    // 2) SSD chunked scan (MFMA, 4-wave cooperative; conv fused into p1 only,
    //    p3 consumes p1's exported X^T)
    ssd_phase1<<<B_N * NHEADS * NC, 256, 0, stream>>>(
        projb, dtf, conv_w, conv_b, A_log, dt_bias, hl, Pc, LaBuf, xT);
    ssd_phase2<<<B_N * NHEADS * 16, 256, 0, stream>>>(hl, Pc);
    ssd_phase3<<<B_N * NHEADS * NC, 256, 0, stream>>>(
        projb, xT, hl, LaBuf, yzbf);

    // 3) out_proj: out = yz @ W_out^T  (M=4096, N=512, K=1024), 512 blocks (2/CU)
    gemm_mfma_bt<64, 64, false, false><<<dim3(DMODEL / 64, M / 64), 256, 0, stream>>>(
        yzbf, wobf, out, nullptr, nullptr, M, DMODEL, DINNER);
}

// Round 12
// 147.290 us; speedup vs baseline: 4.5910x; 1.0154x over previous
//
#include <hip/hip_runtime.h>
#include <cstdint>
#include <cstddef>

// ---- problem constants ----
#define B_N     2
#define L_N     2048
#define DMODEL  512
#define DINNER  1024
#define DSTATE  64
#define NHEADS  16
#define EPROJ   2192      // 2*DINNER + 2*DSTATE + NHEADS
#define PB      2176      // bf16 proj row stride (z,x,B,C)
#define OFF_Z   0
#define OFF_XP  1024
#define OFF_B   2048
#define OFF_C   2112
#define LC      64        // scan chunk length (= matmul tile)
#define NC      32        // L_N / LC

typedef unsigned short u16;
typedef unsigned int   u32;
typedef __attribute__((ext_vector_type(8))) short short8;   // 8 bf16 (4 VGPRs)
typedef __attribute__((ext_vector_type(4))) float floatx4;  // MFMA acc

__device__ __forceinline__ float silu_f(float v) { return v / (1.f + __expf(-v)); }

__device__ __forceinline__ u16 f2bf(float f) {
    union { float f; uint32_t u; } v; v.f = f;
    uint32_t r = (v.u + 0x7FFFu + ((v.u >> 16) & 1u)) >> 16;  // RNE
    return (u16)r;
}

__device__ __forceinline__ float bf2f(u16 b) {
    union { u32 u; float f; } v; v.u = (u32)b << 16; return v.f;
}

__device__ __forceinline__ u32 pack2(float lo, float hi) {
    return (u32)f2bf(lo) | ((u32)f2bf(hi) << 16);
}

__device__ __forceinline__ float lane_bcast(float v, int n) {
    union { float f; uint32_t u; } a, b;
    a.f = v;
    b.u = __builtin_amdgcn_readlane(a.u, n);
    return b.f;
}

// read bf16 fragment A[row][k0..k0+7] from pair-packed LDS tile (stride 33 dwords)
__device__ __forceinline__ short8 frag_ld(const u32* s, int row, int k0) {
    const u32* q = s + row * 33 + (k0 >> 1);
    union { u32 u[4]; short8 v; } r;
    r.u[0] = q[0]; r.u[1] = q[1]; r.u[2] = q[2]; r.u[3] = q[3];
    return r.v;
}

__device__ __forceinline__ void gload_lds16(const u16* g, u16* s) {
    __builtin_amdgcn_global_load_lds(
        (const __attribute__((address_space(1))) void*)g,
        (__attribute__((address_space(3))) void*)s,
        16, 0, 0);
}

// =====================================================================
// fused fp32 -> bf16 cast for x, W_in, W_out (one launch). n's in float4 quads.
// =====================================================================
__global__ __launch_bounds__(256) void cast3_kern(
    const float* __restrict__ s0, u16* __restrict__ d0, int n0,
    const float* __restrict__ s1, u16* __restrict__ d1, int n1,
    const float* __restrict__ s2, u16* __restrict__ d2, int n2)
{
    int i = blockIdx.x * 256 + threadIdx.x;
    const float* s; u16* d;
    if (i < n0)           { s = s0; d = d0; }
    else if (i < n0 + n1) { i -= n0; s = s1; d = d1; }
    else                  { i -= n0 + n1; if (i >= n2) return; s = s2; d = d2; }
    float4 v = ((const float4*)s)[i];
    ushort4 o;
    o.x = f2bf(v.x); o.y = f2bf(v.y); o.z = f2bf(v.z); o.w = f2bf(v.w);
    ((ushort4*)d)[i] = o;
}

// =====================================================================
// bf16 MFMA GEMM (m97 pattern), generic BM/BN (BN any multiple of 32).
//   C = A[M,K] @ Bt[N,K]^T.  4 waves as 2x2; wave tile (BM/2)x(BN/2).
// Staging: 16-row groups round-robined across waves (handles BN=160).
// PSPLIT epilogue: col<2176 -> bf16 projb; 2176..2191 -> f32 dtf.
// =====================================================================
template<int BM, int BN, bool GUARD, bool PSPLIT>
__global__ __launch_bounds__(256, 2) void gemm_mfma_bt(
    const u16* __restrict__ A, const u16* __restrict__ Bt,
    float* __restrict__ Cf, u16* __restrict__ Cb, float* __restrict__ Dt,
    int M, int N, int K)
{
    constexpr int MI = BM / 32;
    constexpr int NI = BN / 32;
    __shared__ u16 As[BM * 32];
    __shared__ u16 Bs[BN * 32];

    const int tid = threadIdx.x;
    const int w   = tid >> 6;
    const int ln  = tid & 63;
    const int wm  = w >> 1, wn = w & 1;
    const int bm  = blockIdx.y * BM;
    const int bn  = blockIdx.x * BN;

    const int srow = ln >> 2;          // 16 rows per wave-load group
    const int skq  = (ln & 3) * 8;
    const int fr = ln & 15;
    const int fq = (ln >> 4) * 8;

    floatx4 acc[MI][NI];
    const floatx4 fzero = {0.f, 0.f, 0.f, 0.f};
    #pragma unroll
    for (int mi = 0; mi < MI; ++mi)
        #pragma unroll
        for (int ni = 0; ni < NI; ++ni) acc[mi][ni] = fzero;

    for (int k0 = 0; k0 < K; k0 += 32) {
        #pragma unroll
        for (int g = 0; g < BM / 16; ++g) {
            if ((g & 3) != w) continue;        // group -> wave round-robin
            gload_lds16(A + (size_t)(bm + g * 16 + srow) * K + k0 + skq,
                        &As[g * 16 * 32]);
        }
        #pragma unroll
        for (int g = 0; g < BN / 16; ++g) {
            if ((g & 3) != w) continue;
            int rn = bn + g * 16 + srow;
            if (GUARD) rn = (rn < N) ? rn : (N - 1);
            gload_lds16(Bt + (size_t)rn * K + k0 + skq,
                        &Bs[g * 16 * 32]);
        }
        __syncthreads();

        short8 af[MI], bf[NI];
        #pragma unroll
        for (int mi = 0; mi < MI; ++mi)
            af[mi] = *(const short8*)&As[(wm * (BM / 2) + mi * 16 + fr) * 32 + fq];
        #pragma unroll
        for (int ni = 0; ni < NI; ++ni)
            bf[ni] = *(const short8*)&Bs[(wn * (BN / 2) + ni * 16 + fr) * 32 + fq];
        #pragma unroll
        for (int mi = 0; mi < MI; ++mi)
            #pragma unroll
            for (int ni = 0; ni < NI; ++ni)
                acc[mi][ni] = __builtin_amdgcn_mfma_f32_16x16x32_bf16(
                    af[mi], bf[ni], acc[mi][ni], 0, 0, 0);
        __syncthreads();
    }

    const int cr = (ln >> 4) * 4;
    const int cc = ln & 15;
    #pragma unroll
    for (int mi = 0; mi < MI; ++mi) {
        const int row0 = bm + wm * (BM / 2) + mi * 16 + cr;
        #pragma unroll
        for (int ni = 0; ni < NI; ++ni) {
            const int col = bn + wn * (BN / 2) + ni * 16 + cc;
            #pragma unroll
            for (int r = 0; r < 4; ++r) {
                const int row = row0 + r;
                const float v = acc[mi][ni][r];
                if (PSPLIT) {
                    if (col < PB)
                        Cb[(size_t)row * PB + col] = f2bf(v);
                    else if (col < EPROJ)
                        Dt[(size_t)row * 16 + (col - PB)] = v;
                } else {
                    Cf[(size_t)row * N + col] = v;
                }
            }
        }
    }
}

// =====================================================================
// SSD phase 1 — 4-wave cooperative block per (b,h,chunk):
//   conv+silu via register sliding window over DIRECT global x reads
//   (no LDS slab, no scalar ds_read): wave w owns s in [16w,16w+16),
//   3-reg window + 2 new rows per step. Exports conv'd X^T for phase3.
//   La = cumsum(logdA);  Hc = (e^(La63-La_s) B)^T @ X  (MFMA)
// =====================================================================
__global__ __launch_bounds__(256) void ssd_phase1(
    const u16* __restrict__ projb, const float* __restrict__ dtf,
    const float* __restrict__ cw, const float* __restrict__ cb,
    const float* __restrict__ A_log, const float* __restrict__ dt_bias,
    float* __restrict__ hl, float* __restrict__ Pc, float* __restrict__ LaBuf,
    u32* __restrict__ xT)
{
    __shared__ u32 sBD[64 * 33];   // (e^(La63-La_s) B[s][n])^T : [n][s-pair]
    __shared__ u32 sXt[64 * 33];   // X^T: [p][s-pair]

    const int bid = blockIdx.x;               // ((b*16+h)*32 + c)
    const int c = bid & (NC - 1);
    const int h = (bid >> 5) & (NHEADS - 1);
    const int b = bid >> 9;
    const int tid = threadIdx.x;
    const int w = tid >> 6, ln = tid & 63;
    const int a = ln & 15, q = ln >> 4;
    const size_t r0 = (size_t)b * L_N + c * LC;

    // logdA + inclusive cumsum (redundant per wave; all waves identical)
    float dt = dtf[(r0 + ln) * 16 + h] + dt_bias[h];
    float sp = (dt > 15.f) ? dt : log1pf(__expf(dt));
    float La = sp * (-__expf(A_log[h]));
    #pragma unroll
    for (int d = 1; d < 64; d <<= 1) {
        float up = __shfl_up(La, d, 64);
        if (ln >= d) La += up;
    }
    if (w == 0) LaBuf[(size_t)bid * 64 + ln] = La;
    const float La63 = lane_bcast(La, 63);

    const int ch = h * 64 + ln;
    const float4 w4 = *(const float4*)(cw + ch * 4);
    const float bias = cb[ch];
    const u16* xcol = projb + OFF_XP + ch;     // column base for x reads
    const size_t bbase = (size_t)b * L_N;

    // rolling window: xr[0..2] = x at local rows (s-3, s-2, s-1); s0 = 16w
    float xr[3];
    #pragma unroll
    for (int i = 0; i < 3; ++i) {
        const int tl = c * LC + 16 * w - 3 + i;
        xr[i] = (tl >= 0) ? bf2f(xcol[(bbase + tl) * PB]) : 0.f;
    }

    // staging: wave w covers s-pairs [w*8, w*8+8); conv+silu inline
    #pragma unroll
    for (int j = 0; j < 8; ++j) {
        const int sp_ = w * 8 + j, s = sp_ * 2;
        const float xa = bf2f(xcol[(r0 + s) * PB]);
        const float xb = bf2f(xcol[(r0 + s + 1) * PB]);
        float a0 = bias, a1 = bias;
        a0 += xr[0] * w4.x; a0 += xr[1] * w4.y; a0 += xr[2] * w4.z; a0 += xa * w4.w;
        a1 += xr[1] * w4.x; a1 += xr[2] * w4.y; a1 += xa * w4.z;   a1 += xb * w4.w;
        xr[0] = xr[2]; xr[1] = xa; xr[2] = xb;
        const float x0 = silu_f(a0), x1 = silu_f(a1);
        const u32 xp = pack2(x0, x1);
        sXt[ln * 33 + sp_] = xp;
        xT[(size_t)bid * 2048 + sp_ * 64 + ln] = xp;   // export for phase3
        const float w0 = __expf(La63 - lane_bcast(La, s));
        const float w1 = __expf(La63 - lane_bcast(La, s + 1));
        const float b0 = bf2f(projb[(r0 + s) * PB + OFF_B + ln]) * w0;
        const float b1 = bf2f(projb[(r0 + s + 1) * PB + OFF_B + ln]) * w1;
        sBD[ln * 33 + sp_] = pack2(b0, b1);
    }
    __syncthreads();

    // MFMA: wave w computes output tile-row tm=w (rows n in [16w,16w+16))
    short8 af[2], bf[4][2];
    #pragma unroll
    for (int ks = 0; ks < 2; ++ks)
        af[ks] = frag_ld(sBD, w * 16 + a, ks * 32 + q * 8);
    #pragma unroll
    for (int tn = 0; tn < 4; ++tn)
        #pragma unroll
        for (int ks = 0; ks < 2; ++ks)
            bf[tn][ks] = frag_ld(sXt, tn * 16 + a, ks * 32 + q * 8);

    const floatx4 fzero = {0.f, 0.f, 0.f, 0.f};
    floatx4 acc[4];
    #pragma unroll
    for (int tn = 0; tn < 4; ++tn) {
        acc[tn] = fzero;
        #pragma unroll
        for (int ks = 0; ks < 2; ++ks)
            acc[tn] = __builtin_amdgcn_mfma_f32_16x16x32_bf16(
                af[ks], bf[tn][ks], acc[tn], 0, 0, 0);
    }

    float* hp = hl + (size_t)bid * (DSTATE * 64);
    #pragma unroll
    for (int tn = 0; tn < 4; ++tn)
        #pragma unroll
        for (int r = 0; r < 4; ++r)
            hp[(w * 16 + q * 4 + r) * 64 + tn * 16 + a] = acc[tn][r];
    if (tid == 0) Pc[bid] = __expf(La63);
}

// =====================================================================
// SSD phase 2 — element-parallel inter-chunk carry, in place over hl.
// =====================================================================
__global__ __launch_bounds__(256) void ssd_phase2(
    float* __restrict__ hl, const float* __restrict__ Pc)
{
    const int bid = blockIdx.x;               // bh*16 + eg
    const int bh = bid >> 4;
    const int e = (bid & 15) * 256 + threadIdx.x;   // state element 0..4095
    const size_t base = (size_t)(bh * NC) * 4096 + e;

    float v[NC];
    #pragma unroll
    for (int c = 0; c < NC; ++c)
        v[c] = hl[base + (size_t)c * 4096];

    float carry = 0.f;
    #pragma unroll
    for (int c = 0; c < NC; ++c) {
        const float cur = v[c];
        v[c] = carry;                          // h_start entering chunk c
        carry = fmaf(Pc[bh * NC + c], carry, cur);
    }

    #pragma unroll
    for (int c = 0; c < NC; ++c)
        hl[base + (size_t)c * 4096] = v[c];
}

// =====================================================================
// SSD phase 3 — 4-wave cooperative block per (b,h,chunk):
//   X^T comes precomputed from phase1 (straight coalesced copy);
//   S^T = B @ C;  W[i][s] = S[i,s] e^(La_i-La_s) (s<=i)
//   Y = diag(e^La) C @ h_start^T + W @ X^T;  yz = Y * silu(z)
// =====================================================================
__global__ __launch_bounds__(256) void ssd_phase3(
    const u16* __restrict__ projb, const u32* __restrict__ xT,
    const float* __restrict__ hl, const float* __restrict__ LaBuf,
    u16* __restrict__ yz)
{
    __shared__ char lds[34048];
    u32* sBW   = (u32*)lds;              // B natural, then W (aliased)
    u32* sC    = (u32*)(lds + 8448);     // C natural [i][n-pair]
    u32* sXt   = (u32*)(lds + 16896);    // X^T [p][s-pair]
    u32* sH    = (u32*)(lds + 25344);    // h_start^T [p][n-pair]
    float* sLaF = (float*)(lds + 33792); // La[64]
    float* sY  = (float*)(lds + 8448);   // f32 [i][p] 64x66, aliases sC+sXt (epilogue)

    const int bid = blockIdx.x;
    const int c = bid & (NC - 1);
    const int h = (bid >> 5) & (NHEADS - 1);
    const int b = bid >> 9;
    const int tid = threadIdx.x;
    const int w = tid >> 6, ln = tid & 63;
    const int a = ln & 15, q = ln >> 4;
    const int hw = ln >> 5, k32 = ln & 31;
    const size_t r0 = (size_t)b * L_N + c * LC;

    if (tid < 64) sLaF[tid] = LaBuf[(size_t)bid * 64 + tid];

    // single staging pass: B, C natural (raw copies); X^T copy; H^T pack
    const float* hs = hl + (size_t)bid * 4096;
    #pragma unroll
    for (int j = 0; j < 8; ++j) {
        const int rp = w * 8 + j;
        const int row = rp * 2 + hw;
        sBW[row * 33 + k32] = *(const u32*)(projb + (r0 + row) * PB + OFF_B + 2 * k32);
        sC [row * 33 + k32] = *(const u32*)(projb + (r0 + row) * PB + OFF_C + 2 * k32);
        sXt[ln * 33 + rp] = xT[(size_t)bid * 2048 + rp * 64 + ln];
        sH [ln * 33 + rp] = pack2(hs[(2 * rp) * 64 + ln], hs[(2 * rp + 1) * 64 + ln]);
    }
    __syncthreads();

    const floatx4 fzero = {0.f, 0.f, 0.f, 0.f};

    // ---- m1: S^T tiles [tm][tn=w], tm<=w ----
    short8 cfr[2], bfr[4][2];
    #pragma unroll
    for (int ks = 0; ks < 2; ++ks)
        cfr[ks] = frag_ld(sC, w * 16 + a, ks * 32 + q * 8);
    #pragma unroll
    for (int tm = 0; tm < 4; ++tm)
        if (tm <= w)
            #pragma unroll
            for (int ks = 0; ks < 2; ++ks)
                bfr[tm][ks] = frag_ld(sBW, tm * 16 + a, ks * 32 + q * 8);
    floatx4 accS[4];
    #pragma unroll
    for (int tm = 0; tm < 4; ++tm) {
        if (tm > w) continue;
        accS[tm] = fzero;
        #pragma unroll
        for (int ks = 0; ks < 2; ++ks)
            accS[tm] = __builtin_amdgcn_mfma_f32_16x16x32_bf16(
                bfr[tm][ks], cfr[ks], accS[tm], 0, 0, 0);
    }
    __syncthreads();   // all waves done reading B before W overwrite

    // ---- build W rows i in [16w,16w+16) ----
    {
        const int i = w * 16 + a;
        const float Li = sLaF[i];
        #pragma unroll
        for (int tm = 0; tm < 4; ++tm) {
            const int d0 = i * 33 + tm * 8 + q * 2;
            if (tm > w) {
                sBW[d0] = 0; sBW[d0 + 1] = 0;
            } else {
                const float4 Ls = *(const float4*)(sLaF + tm * 16 + q * 4);
                float v[4];
                #pragma unroll
                for (int r = 0; r < 4; ++r) {
                    const int s = tm * 16 + q * 4 + r;
                    const float ww = (s <= i) ? __expf(Li - ((const float*)&Ls)[r]) : 0.f;
                    v[r] = accS[tm][r] * ww;
                }
                sBW[d0]     = pack2(v[0], v[1]);
                sBW[d0 + 1] = pack2(v[2], v[3]);
            }
        }
    }

    // ---- m4: accY = C @ h_start^T (row-tile w), scale rows by e^La_i ----
    short8 hfr[4][2];
    #pragma unroll
    for (int tp = 0; tp < 4; ++tp)
        #pragma unroll
        for (int ks = 0; ks < 2; ++ks)
            hfr[tp][ks] = frag_ld(sH, tp * 16 + a, ks * 32 + q * 8);
    floatx4 accY[4];
    #pragma unroll
    for (int tp = 0; tp < 4; ++tp) {
        accY[tp] = fzero;
        #pragma unroll
        for (int ks = 0; ks < 2; ++ks)
            accY[tp] = __builtin_amdgcn_mfma_f32_16x16x32_bf16(
                cfr[ks], hfr[tp][ks], accY[tp], 0, 0, 0);
    }
    {
        const float4 Ls = *(const float4*)(sLaF + w * 16 + q * 4);
        float e4[4];
        #pragma unroll
        for (int r = 0; r < 4; ++r) e4[r] = __expf(((const float*)&Ls)[r]);
        #pragma unroll
        for (int tp = 0; tp < 4; ++tp)
            #pragma unroll
            for (int r = 0; r < 4; ++r) accY[tp][r] *= e4[r];
    }

    // ---- m2: accY += W @ X^T (wave reads only its own W rows) ----
    short8 wfr[2], xfr[4][2];
    #pragma unroll
    for (int ks = 0; ks < 2; ++ks)
        wfr[ks] = frag_ld(sBW, w * 16 + a, ks * 32 + q * 8);
    #pragma unroll
    for (int tp = 0; tp < 4; ++tp)
        #pragma unroll
        for (int ks = 0; ks < 2; ++ks)
            xfr[tp][ks] = frag_ld(sXt, tp * 16 + a, ks * 32 + q * 8);
    #pragma unroll
    for (int tp = 0; tp < 4; ++tp)
        #pragma unroll
        for (int ks = 0; ks < 2; ++ks)
            accY[tp] = __builtin_amdgcn_mfma_f32_16x16x32_bf16(
                wfr[ks], xfr[tp][ks], accY[tp], 0, 0, 0);
    __syncthreads();   // all frag reads of sC/sXt done; safe to alias as sY

    // ---- epilogue: own-rows LDS round-trip, gate (bf16 z), bf16 store ----
    #pragma unroll
    for (int tp = 0; tp < 4; ++tp)
        #pragma unroll
        for (int r = 0; r < 4; ++r)
            sY[(w * 16 + q * 4 + r) * 66 + tp * 16 + a] = accY[tp][r];
    #pragma unroll
    for (int ii = 0; ii < 16; ++ii) {
        const int i = w * 16 + ii;
        const float y = sY[i * 66 + ln];
        const float z = bf2f(projb[(r0 + i) * PB + OFF_Z + h * 64 + ln]);
        yz[(r0 + i) * DINNER + h * 64 + ln] = f2bf(y * silu_f(z));
    }
}

// =====================================================================
extern "C" void kernel_launch(void* const* d_in, const int* in_sizes, int n_in,
                              void* d_out, int out_size, void* d_ws, size_t ws_size,
                              hipStream_t stream)
{
    const float* x       = (const float*)d_in[0];
    const float* W_in    = (const float*)d_in[1];
    const float* conv_w  = (const float*)d_in[2];
    const float* conv_b  = (const float*)d_in[3];
    const float* A_log   = (const float*)d_in[4];
    const float* dt_bias = (const float*)d_in[5];
    const float* W_out   = (const float*)d_in[6];
    float* out = (float*)d_out;

    // workspace layout (~59 MB)
    u16*   projb = (u16*)d_ws;                                  // 4096*2176 bf16
    float* dtf   = (float*)(projb + (size_t)4096 * PB);         // 4096*16 f32
    float* hl    = dtf + (size_t)4096 * 16;                     // 1024*4096 f32
    float* Pc    = hl + (size_t)1024 * 4096;                    // 1024
    float* LaBuf = Pc + 1024;                                   // 1024*64
    u16*   xbf   = (u16*)(LaBuf + 1024 * 64);                   // 4096*512 bf16
    u16*   wibf  = xbf + (size_t)4096 * DMODEL;                 // 2192*512 bf16
    u16*   wobf  = wibf + (size_t)EPROJ * DMODEL;               // 512*1024 bf16
    u16*   yzbf  = wobf + (size_t)DMODEL * DINNER;              // 4096*1024 bf16
    u32*   xT    = (u32*)(yzbf + (size_t)4096 * DINNER);        // 1024*2048 u32 (conv'd X^T)

    const int M = B_N * L_N;  // 4096
    const int n0 = M * DMODEL / 4, n1 = EPROJ * DMODEL / 4, n2 = DMODEL * DINNER / 4;

    // 0) fused casts
    cast3_kern<<<(n0 + n1 + n2 + 255) / 256, 256, 0, stream>>>(
        x, xbf, n0, W_in, wibf, n1, W_out, wobf, n2);

    // 1) in_proj: proj = x @ W_in^T (M=4096, N=2192, K=512), BN=160 -> 448 blocks
    gemm_mfma_bt<128, 160, true, true><<<dim3(14, M / 128), 256, 0, stream>>>(
        xbf, wibf, nullptr, projb, dtf, M, EPROJ, DMODEL);

    // 2) SSD chunked scan (MFMA, 4-wave cooperative; conv in p1 via register
    //    sliding window over direct global reads; p3 consumes p1's X^T)
    ssd_phase1<<<B_N * NHEADS * NC, 256, 0, stream>>>(
        projb, dtf, conv_w, conv_b, A_log, dt_bias, hl, Pc, LaBuf, xT);
    ssd_phase2<<<B_N * NHEADS * 16, 256, 0, stream>>>(hl, Pc);
    ssd_phase3<<<B_N * NHEADS * NC, 256, 0, stream>>>(
        projb, xT, hl, LaBuf, yzbf);

    // 3) out_proj: out = yz @ W_out^T  (M=4096, N=512, K=1024), 512 blocks (2/CU)
    gemm_mfma_bt<64, 64, false, false><<<dim3(DMODEL / 64, M / 64), 256, 0, stream>>>(
        yzbf, wobf, out, nullptr, nullptr, M, DMODEL, DINNER);
}

// Round 13
// 143.574 us; speedup vs baseline: 4.7098x; 1.0259x over previous
//
#include <hip/hip_runtime.h>
#include <cstdint>
#include <cstddef>

// ---- problem constants ----
#define B_N     2
#define L_N     2048
#define DMODEL  512
#define DINNER  1024
#define DSTATE  64
#define NHEADS  16
#define EPROJ   2192      // 2*DINNER + 2*DSTATE + NHEADS
#define PB      2176      // bf16 proj row stride (z,x,B,C)
#define OFF_Z   0
#define OFF_XP  1024
#define OFF_B   2048
#define OFF_C   2112
#define LC      64        // scan chunk length (= matmul tile)
#define NC      32        // L_N / LC

typedef unsigned short u16;
typedef unsigned int   u32;
typedef __attribute__((ext_vector_type(8))) short short8;   // 8 bf16 (4 VGPRs)
typedef __attribute__((ext_vector_type(4))) float floatx4;  // MFMA acc

__device__ __forceinline__ float silu_f(float v) { return v / (1.f + __expf(-v)); }

__device__ __forceinline__ u16 f2bf(float f) {
    union { float f; uint32_t u; } v; v.f = f;
    uint32_t r = (v.u + 0x7FFFu + ((v.u >> 16) & 1u)) >> 16;  // RNE
    return (u16)r;
}

__device__ __forceinline__ float bf2f(u16 b) {
    union { u32 u; float f; } v; v.u = (u32)b << 16; return v.f;
}

__device__ __forceinline__ u32 pack2(float lo, float hi) {
    return (u32)f2bf(lo) | ((u32)f2bf(hi) << 16);
}

__device__ __forceinline__ float lane_bcast(float v, int n) {
    union { float f; uint32_t u; } a, b;
    a.f = v;
    b.u = __builtin_amdgcn_readlane(a.u, n);
    return b.f;
}

// read bf16 fragment A[row][k0..k0+7] from pair-packed LDS tile (stride 33 dwords)
__device__ __forceinline__ short8 frag_ld(const u32* s, int row, int k0) {
    const u32* q = s + row * 33 + (k0 >> 1);
    union { u32 u[4]; short8 v; } r;
    r.u[0] = q[0]; r.u[1] = q[1]; r.u[2] = q[2]; r.u[3] = q[3];
    return r.v;
}

__device__ __forceinline__ void gload_lds16(const u16* g, u16* s) {
    __builtin_amdgcn_global_load_lds(
        (const __attribute__((address_space(1))) void*)g,
        (__attribute__((address_space(3))) void*)s,
        16, 0, 0);
}

// =====================================================================
// fused fp32 -> bf16 cast for x, W_in, W_out (one launch). n's in float4 quads.
// =====================================================================
__global__ __launch_bounds__(256) void cast3_kern(
    const float* __restrict__ s0, u16* __restrict__ d0, int n0,
    const float* __restrict__ s1, u16* __restrict__ d1, int n1,
    const float* __restrict__ s2, u16* __restrict__ d2, int n2)
{
    int i = blockIdx.x * 256 + threadIdx.x;
    const float* s; u16* d;
    if (i < n0)           { s = s0; d = d0; }
    else if (i < n0 + n1) { i -= n0; s = s1; d = d1; }
    else                  { i -= n0 + n1; if (i >= n2) return; s = s2; d = d2; }
    float4 v = ((const float4*)s)[i];
    ushort4 o;
    o.x = f2bf(v.x); o.y = f2bf(v.y); o.z = f2bf(v.z); o.w = f2bf(v.w);
    ((ushort4*)d)[i] = o;
}

// =====================================================================
// bf16 MFMA GEMM (m97 pattern), BK=64 via TWO 32-k LDS panels:
// one barrier pair per 64-k (half the barriers of BK=32) while keeping
// each panel's 64 B row stride (2-way bank aliasing = free; flat 128 B
// rows would conflict, and gload_lds16 forbids padding).
//   C = A[M,K] @ Bt[N,K]^T.  4 waves as 2x2; wave tile (BM/2)x(BN/2).
// K % 64 == 0 assumed. PSPLIT epilogue: col<2176 -> bf16 projb;
// 2176..2191 -> f32 dtf.
// =====================================================================
template<int BM, int BN, bool GUARD, bool PSPLIT>
__global__ __launch_bounds__(256, 2) void gemm_mfma_bt(
    const u16* __restrict__ A, const u16* __restrict__ Bt,
    float* __restrict__ Cf, u16* __restrict__ Cb, float* __restrict__ Dt,
    int M, int N, int K)
{
    constexpr int MI = BM / 32;
    constexpr int NI = BN / 32;
    __shared__ u16 As[2][BM * 32];
    __shared__ u16 Bs[2][BN * 32];

    const int tid = threadIdx.x;
    const int w   = tid >> 6;
    const int ln  = tid & 63;
    const int wm  = w >> 1, wn = w & 1;
    const int bm  = blockIdx.y * BM;
    const int bn  = blockIdx.x * BN;

    const int srow = ln >> 2;          // 16 rows per wave-load group
    const int skq  = (ln & 3) * 8;
    const int fr = ln & 15;
    const int fq = (ln >> 4) * 8;

    floatx4 acc[MI][NI];
    const floatx4 fzero = {0.f, 0.f, 0.f, 0.f};
    #pragma unroll
    for (int mi = 0; mi < MI; ++mi)
        #pragma unroll
        for (int ni = 0; ni < NI; ++ni) acc[mi][ni] = fzero;

    for (int k0 = 0; k0 < K; k0 += 64) {
        #pragma unroll
        for (int p = 0; p < 2; ++p) {
            const int kp = k0 + p * 32;
            #pragma unroll
            for (int g = 0; g < BM / 16; ++g) {
                if ((g & 3) != w) continue;    // group -> wave round-robin
                gload_lds16(A + (size_t)(bm + g * 16 + srow) * K + kp + skq,
                            &As[p][g * 16 * 32]);
            }
            #pragma unroll
            for (int g = 0; g < BN / 16; ++g) {
                if ((g & 3) != w) continue;
                int rn = bn + g * 16 + srow;
                if (GUARD) rn = (rn < N) ? rn : (N - 1);
                gload_lds16(Bt + (size_t)rn * K + kp + skq,
                            &Bs[p][g * 16 * 32]);
            }
        }
        __syncthreads();

        #pragma unroll
        for (int p = 0; p < 2; ++p) {
            short8 af[MI], bf[NI];
            #pragma unroll
            for (int mi = 0; mi < MI; ++mi)
                af[mi] = *(const short8*)&As[p][(wm * (BM / 2) + mi * 16 + fr) * 32 + fq];
            #pragma unroll
            for (int ni = 0; ni < NI; ++ni)
                bf[ni] = *(const short8*)&Bs[p][(wn * (BN / 2) + ni * 16 + fr) * 32 + fq];
            #pragma unroll
            for (int mi = 0; mi < MI; ++mi)
                #pragma unroll
                for (int ni = 0; ni < NI; ++ni)
                    acc[mi][ni] = __builtin_amdgcn_mfma_f32_16x16x32_bf16(
                        af[mi], bf[ni], acc[mi][ni], 0, 0, 0);
        }
        __syncthreads();
    }

    const int cr = (ln >> 4) * 4;
    const int cc = ln & 15;
    #pragma unroll
    for (int mi = 0; mi < MI; ++mi) {
        const int row0 = bm + wm * (BM / 2) + mi * 16 + cr;
        #pragma unroll
        for (int ni = 0; ni < NI; ++ni) {
            const int col = bn + wn * (BN / 2) + ni * 16 + cc;
            #pragma unroll
            for (int r = 0; r < 4; ++r) {
                const int row = row0 + r;
                const float v = acc[mi][ni][r];
                if (PSPLIT) {
                    if (col < PB)
                        Cb[(size_t)row * PB + col] = f2bf(v);
                    else if (col < EPROJ)
                        Dt[(size_t)row * 16 + (col - PB)] = v;
                } else {
                    Cf[(size_t)row * N + col] = v;
                }
            }
        }
    }
}

// =====================================================================
// SSD phase 1 — 4-wave cooperative block per (b,h,chunk):
//   conv+silu via register sliding window over DIRECT global x reads
//   (no LDS slab): wave w owns s in [16w,16w+16). Exports conv'd X^T.
//   La = cumsum(logdA);  Hc = (e^(La63-La_s) B)^T @ X  (MFMA)
// =====================================================================
__global__ __launch_bounds__(256) void ssd_phase1(
    const u16* __restrict__ projb, const float* __restrict__ dtf,
    const float* __restrict__ cw, const float* __restrict__ cb,
    const float* __restrict__ A_log, const float* __restrict__ dt_bias,
    float* __restrict__ hl, float* __restrict__ Pc, float* __restrict__ LaBuf,
    u32* __restrict__ xT)
{
    __shared__ u32 sBD[64 * 33];   // (e^(La63-La_s) B[s][n])^T : [n][s-pair]
    __shared__ u32 sXt[64 * 33];   // X^T: [p][s-pair]

    const int bid = blockIdx.x;               // ((b*16+h)*32 + c)
    const int c = bid & (NC - 1);
    const int h = (bid >> 5) & (NHEADS - 1);
    const int b = bid >> 9;
    const int tid = threadIdx.x;
    const int w = tid >> 6, ln = tid & 63;
    const int a = ln & 15, q = ln >> 4;
    const size_t r0 = (size_t)b * L_N + c * LC;

    // logdA + inclusive cumsum (redundant per wave; all waves identical)
    float dt = dtf[(r0 + ln) * 16 + h] + dt_bias[h];
    float sp = (dt > 15.f) ? dt : log1pf(__expf(dt));
    float La = sp * (-__expf(A_log[h]));
    #pragma unroll
    for (int d = 1; d < 64; d <<= 1) {
        float up = __shfl_up(La, d, 64);
        if (ln >= d) La += up;
    }
    if (w == 0) LaBuf[(size_t)bid * 64 + ln] = La;
    const float La63 = lane_bcast(La, 63);

    const int ch = h * 64 + ln;
    const float4 w4 = *(const float4*)(cw + ch * 4);
    const float bias = cb[ch];
    const u16* xcol = projb + OFF_XP + ch;     // column base for x reads
    const size_t bbase = (size_t)b * L_N;

    // rolling window: xr[0..2] = x at local rows (s-3, s-2, s-1); s0 = 16w
    float xr[3];
    #pragma unroll
    for (int i = 0; i < 3; ++i) {
        const int tl = c * LC + 16 * w - 3 + i;
        xr[i] = (tl >= 0) ? bf2f(xcol[(bbase + tl) * PB]) : 0.f;
    }

    // staging: wave w covers s-pairs [w*8, w*8+8); conv+silu inline
    #pragma unroll
    for (int j = 0; j < 8; ++j) {
        const int sp_ = w * 8 + j, s = sp_ * 2;
        const float xa = bf2f(xcol[(r0 + s) * PB]);
        const float xb = bf2f(xcol[(r0 + s + 1) * PB]);
        float a0 = bias, a1 = bias;
        a0 += xr[0] * w4.x; a0 += xr[1] * w4.y; a0 += xr[2] * w4.z; a0 += xa * w4.w;
        a1 += xr[1] * w4.x; a1 += xr[2] * w4.y; a1 += xa * w4.z;   a1 += xb * w4.w;
        xr[0] = xr[2]; xr[1] = xa; xr[2] = xb;
        const float x0 = silu_f(a0), x1 = silu_f(a1);
        const u32 xp = pack2(x0, x1);
        sXt[ln * 33 + sp_] = xp;
        xT[(size_t)bid * 2048 + sp_ * 64 + ln] = xp;   // export for phase3
        const float w0 = __expf(La63 - lane_bcast(La, s));
        const float w1 = __expf(La63 - lane_bcast(La, s + 1));
        const float b0 = bf2f(projb[(r0 + s) * PB + OFF_B + ln]) * w0;
        const float b1 = bf2f(projb[(r0 + s + 1) * PB + OFF_B + ln]) * w1;
        sBD[ln * 33 + sp_] = pack2(b0, b1);
    }
    __syncthreads();

    // MFMA: wave w computes output tile-row tm=w (rows n in [16w,16w+16))
    short8 af[2], bf[4][2];
    #pragma unroll
    for (int ks = 0; ks < 2; ++ks)
        af[ks] = frag_ld(sBD, w * 16 + a, ks * 32 + q * 8);
    #pragma unroll
    for (int tn = 0; tn < 4; ++tn)
        #pragma unroll
        for (int ks = 0; ks < 2; ++ks)
            bf[tn][ks] = frag_ld(sXt, tn * 16 + a, ks * 32 + q * 8);

    const floatx4 fzero = {0.f, 0.f, 0.f, 0.f};
    floatx4 acc[4];
    #pragma unroll
    for (int tn = 0; tn < 4; ++tn) {
        acc[tn] = fzero;
        #pragma unroll
        for (int ks = 0; ks < 2; ++ks)
            acc[tn] = __builtin_amdgcn_mfma_f32_16x16x32_bf16(
                af[ks], bf[tn][ks], acc[tn], 0, 0, 0);
    }

    float* hp = hl + (size_t)bid * (DSTATE * 64);
    #pragma unroll
    for (int tn = 0; tn < 4; ++tn)
        #pragma unroll
        for (int r = 0; r < 4; ++r)
            hp[(w * 16 + q * 4 + r) * 64 + tn * 16 + a] = acc[tn][r];
    if (tid == 0) Pc[bid] = __expf(La63);
}

// =====================================================================
// SSD phase 2 — element-parallel inter-chunk carry, in place over hl.
// =====================================================================
__global__ __launch_bounds__(256) void ssd_phase2(
    float* __restrict__ hl, const float* __restrict__ Pc)
{
    const int bid = blockIdx.x;               // bh*16 + eg
    const int bh = bid >> 4;
    const int e = (bid & 15) * 256 + threadIdx.x;   // state element 0..4095
    const size_t base = (size_t)(bh * NC) * 4096 + e;

    float v[NC];
    #pragma unroll
    for (int c = 0; c < NC; ++c)
        v[c] = hl[base + (size_t)c * 4096];

    float carry = 0.f;
    #pragma unroll
    for (int c = 0; c < NC; ++c) {
        const float cur = v[c];
        v[c] = carry;                          // h_start entering chunk c
        carry = fmaf(Pc[bh * NC + c], carry, cur);
    }

    #pragma unroll
    for (int c = 0; c < NC; ++c)
        hl[base + (size_t)c * 4096] = v[c];
}

// =====================================================================
// SSD phase 3 — 4-wave cooperative block per (b,h,chunk):
//   X^T comes precomputed from phase1 (straight coalesced copy);
//   S^T = B @ C;  W[i][s] = S[i,s] e^(La_i-La_s) (s<=i)
//   Y = diag(e^La) C @ h_start^T + W @ X^T;  yz = Y * silu(z)
// =====================================================================
__global__ __launch_bounds__(256) void ssd_phase3(
    const u16* __restrict__ projb, const u32* __restrict__ xT,
    const float* __restrict__ hl, const float* __restrict__ LaBuf,
    u16* __restrict__ yz)
{
    __shared__ char lds[34048];
    u32* sBW   = (u32*)lds;              // B natural, then W (aliased)
    u32* sC    = (u32*)(lds + 8448);     // C natural [i][n-pair]
    u32* sXt   = (u32*)(lds + 16896);    // X^T [p][s-pair]
    u32* sH    = (u32*)(lds + 25344);    // h_start^T [p][n-pair]
    float* sLaF = (float*)(lds + 33792); // La[64]
    float* sY  = (float*)(lds + 8448);   // f32 [i][p] 64x66, aliases sC+sXt (epilogue)

    const int bid = blockIdx.x;
    const int c = bid & (NC - 1);
    const int h = (bid >> 5) & (NHEADS - 1);
    const int b = bid >> 9;
    const int tid = threadIdx.x;
    const int w = tid >> 6, ln = tid & 63;
    const int a = ln & 15, q = ln >> 4;
    const int hw = ln >> 5, k32 = ln & 31;
    const size_t r0 = (size_t)b * L_N + c * LC;

    if (tid < 64) sLaF[tid] = LaBuf[(size_t)bid * 64 + tid];

    // single staging pass: B, C natural (raw copies); X^T copy; H^T pack
    const float* hs = hl + (size_t)bid * 4096;
    #pragma unroll
    for (int j = 0; j < 8; ++j) {
        const int rp = w * 8 + j;
        const int row = rp * 2 + hw;
        sBW[row * 33 + k32] = *(const u32*)(projb + (r0 + row) * PB + OFF_B + 2 * k32);
        sC [row * 33 + k32] = *(const u32*)(projb + (r0 + row) * PB + OFF_C + 2 * k32);
        sXt[ln * 33 + rp] = xT[(size_t)bid * 2048 + rp * 64 + ln];
        sH [ln * 33 + rp] = pack2(hs[(2 * rp) * 64 + ln], hs[(2 * rp + 1) * 64 + ln]);
    }
    __syncthreads();

    const floatx4 fzero = {0.f, 0.f, 0.f, 0.f};

    // ---- m1: S^T tiles [tm][tn=w], tm<=w ----
    short8 cfr[2], bfr[4][2];
    #pragma unroll
    for (int ks = 0; ks < 2; ++ks)
        cfr[ks] = frag_ld(sC, w * 16 + a, ks * 32 + q * 8);
    #pragma unroll
    for (int tm = 0; tm < 4; ++tm)
        if (tm <= w)
            #pragma unroll
            for (int ks = 0; ks < 2; ++ks)
                bfr[tm][ks] = frag_ld(sBW, tm * 16 + a, ks * 32 + q * 8);
    floatx4 accS[4];
    #pragma unroll
    for (int tm = 0; tm < 4; ++tm) {
        if (tm > w) continue;
        accS[tm] = fzero;
        #pragma unroll
        for (int ks = 0; ks < 2; ++ks)
            accS[tm] = __builtin_amdgcn_mfma_f32_16x16x32_bf16(
                bfr[tm][ks], cfr[ks], accS[tm], 0, 0, 0);
    }
    __syncthreads();   // all waves done reading B before W overwrite

    // ---- build W rows i in [16w,16w+16) ----
    {
        const int i = w * 16 + a;
        const float Li = sLaF[i];
        #pragma unroll
        for (int tm = 0; tm < 4; ++tm) {
            const int d0 = i * 33 + tm * 8 + q * 2;
            if (tm > w) {
                sBW[d0] = 0; sBW[d0 + 1] = 0;
            } else {
                const float4 Ls = *(const float4*)(sLaF + tm * 16 + q * 4);
                float v[4];
                #pragma unroll
                for (int r = 0; r < 4; ++r) {
                    const int s = tm * 16 + q * 4 + r;
                    const float ww = (s <= i) ? __expf(Li - ((const float*)&Ls)[r]) : 0.f;
                    v[r] = accS[tm][r] * ww;
                }
                sBW[d0]     = pack2(v[0], v[1]);
                sBW[d0 + 1] = pack2(v[2], v[3]);
            }
        }
    }

    // ---- m4: accY = C @ h_start^T (row-tile w), scale rows by e^La_i ----
    short8 hfr[4][2];
    #pragma unroll
    for (int tp = 0; tp < 4; ++tp)
        #pragma unroll
        for (int ks = 0; ks < 2; ++ks)
            hfr[tp][ks] = frag_ld(sH, tp * 16 + a, ks * 32 + q * 8);
    floatx4 accY[4];
    #pragma unroll
    for (int tp = 0; tp < 4; ++tp) {
        accY[tp] = fzero;
        #pragma unroll
        for (int ks = 0; ks < 2; ++ks)
            accY[tp] = __builtin_amdgcn_mfma_f32_16x16x32_bf16(
                cfr[ks], hfr[tp][ks], accY[tp], 0, 0, 0);
    }
    {
        const float4 Ls = *(const float4*)(sLaF + w * 16 + q * 4);
        float e4[4];
        #pragma unroll
        for (int r = 0; r < 4; ++r) e4[r] = __expf(((const float*)&Ls)[r]);
        #pragma unroll
        for (int tp = 0; tp < 4; ++tp)
            #pragma unroll
            for (int r = 0; r < 4; ++r) accY[tp][r] *= e4[r];
    }

    // ---- m2: accY += W @ X^T (wave reads only its own W rows) ----
    short8 wfr[2], xfr[4][2];
    #pragma unroll
    for (int ks = 0; ks < 2; ++ks)
        wfr[ks] = frag_ld(sBW, w * 16 + a, ks * 32 + q * 8);
    #pragma unroll
    for (int tp = 0; tp < 4; ++tp)
        #pragma unroll
        for (int ks = 0; ks < 2; ++ks)
            xfr[tp][ks] = frag_ld(sXt, tp * 16 + a, ks * 32 + q * 8);
    #pragma unroll
    for (int tp = 0; tp < 4; ++tp)
        #pragma unroll
        for (int ks = 0; ks < 2; ++ks)
            accY[tp] = __builtin_amdgcn_mfma_f32_16x16x32_bf16(
                wfr[ks], xfr[tp][ks], accY[tp], 0, 0, 0);
    __syncthreads();   // all frag reads of sC/sXt done; safe to alias as sY

    // ---- epilogue: own-rows LDS round-trip, gate (bf16 z), bf16 store ----
    #pragma unroll
    for (int tp = 0; tp < 4; ++tp)
        #pragma unroll
        for (int r = 0; r < 4; ++r)
            sY[(w * 16 + q * 4 + r) * 66 + tp * 16 + a] = accY[tp][r];
    #pragma unroll
    for (int ii = 0; ii < 16; ++ii) {
        const int i = w * 16 + ii;
        const float y = sY[i * 66 + ln];
        const float z = bf2f(projb[(r0 + i) * PB + OFF_Z + h * 64 + ln]);
        yz[(r0 + i) * DINNER + h * 64 + ln] = f2bf(y * silu_f(z));
    }
}

// =====================================================================
extern "C" void kernel_launch(void* const* d_in, const int* in_sizes, int n_in,
                              void* d_out, int out_size, void* d_ws, size_t ws_size,
                              hipStream_t stream)
{
    const float* x       = (const float*)d_in[0];
    const float* W_in    = (const float*)d_in[1];
    const float* conv_w  = (const float*)d_in[2];
    const float* conv_b  = (const float*)d_in[3];
    const float* A_log   = (const float*)d_in[4];
    const float* dt_bias = (const float*)d_in[5];
    const float* W_out   = (const float*)d_in[6];
    float* out = (float*)d_out;

    // workspace layout (~59 MB)
    u16*   projb = (u16*)d_ws;                                  // 4096*2176 bf16
    float* dtf   = (float*)(projb + (size_t)4096 * PB);         // 4096*16 f32
    float* hl    = dtf + (size_t)4096 * 16;                     // 1024*4096 f32
    float* Pc    = hl + (size_t)1024 * 4096;                    // 1024
    float* LaBuf = Pc + 1024;                                   // 1024*64
    u16*   xbf   = (u16*)(LaBuf + 1024 * 64);                   // 4096*512 bf16
    u16*   wibf  = xbf + (size_t)4096 * DMODEL;                 // 2192*512 bf16
    u16*   wobf  = wibf + (size_t)EPROJ * DMODEL;               // 512*1024 bf16
    u16*   yzbf  = wobf + (size_t)DMODEL * DINNER;              // 4096*1024 bf16
    u32*   xT    = (u32*)(yzbf + (size_t)4096 * DINNER);        // 1024*2048 u32 (conv'd X^T)

    const int M = B_N * L_N;  // 4096
    const int n0 = M * DMODEL / 4, n1 = EPROJ * DMODEL / 4, n2 = DMODEL * DINNER / 4;

    // 0) fused casts
    cast3_kern<<<(n0 + n1 + n2 + 255) / 256, 256, 0, stream>>>(
        x, xbf, n0, W_in, wibf, n1, W_out, wobf, n2);

    // 1) in_proj: proj = x @ W_in^T (M=4096, N=2192, K=512), BN=160 -> 448 blocks
    gemm_mfma_bt<128, 160, true, true><<<dim3(14, M / 128), 256, 0, stream>>>(
        xbf, wibf, nullptr, projb, dtf, M, EPROJ, DMODEL);

    // 2) SSD chunked scan (MFMA, 4-wave cooperative; conv in p1 via register
    //    sliding window over direct global reads; p3 consumes p1's X^T)
    ssd_phase1<<<B_N * NHEADS * NC, 256, 0, stream>>>(
        projb, dtf, conv_w, conv_b, A_log, dt_bias, hl, Pc, LaBuf, xT);
    ssd_phase2<<<B_N * NHEADS * 16, 256, 0, stream>>>(hl, Pc);
    ssd_phase3<<<B_N * NHEADS * NC, 256, 0, stream>>>(
        projb, xT, hl, LaBuf, yzbf);

    // 3) out_proj: out = yz @ W_out^T  (M=4096, N=512, K=1024), 512 blocks (2/CU)
    gemm_mfma_bt<64, 64, false, false><<<dim3(DMODEL / 64, M / 64), 256, 0, stream>>>(
        yzbf, wobf, out, nullptr, nullptr, M, DMODEL, DINNER);
}

// Round 14
// 136.981 us; speedup vs baseline: 4.9365x; 1.0481x over previous
//
#include <hip/hip_runtime.h>
#include <cstdint>
#include <cstddef>

// ---- problem constants ----
#define B_N     2
#define L_N     2048
#define DMODEL  512
#define DINNER  1024
#define DSTATE  64
#define NHEADS  16
#define EPROJ   2192      // 2*DINNER + 2*DSTATE + NHEADS
#define PB      2176      // bf16 proj row stride (z,x,B,C)
#define OFF_Z   0
#define OFF_XP  1024
#define OFF_B   2048
#define OFF_C   2112
#define LC      64        // scan chunk length (= matmul tile)
#define NC      32        // L_N / LC

typedef unsigned short u16;
typedef unsigned int   u32;
typedef __attribute__((ext_vector_type(8))) short short8;   // 8 bf16 (4 VGPRs)
typedef __attribute__((ext_vector_type(4))) float floatx4;  // MFMA acc

__device__ __forceinline__ float silu_f(float v) { return v / (1.f + __expf(-v)); }

__device__ __forceinline__ u16 f2bf(float f) {
    union { float f; uint32_t u; } v; v.f = f;
    uint32_t r = (v.u + 0x7FFFu + ((v.u >> 16) & 1u)) >> 16;  // RNE
    return (u16)r;
}

__device__ __forceinline__ float bf2f(u16 b) {
    union { u32 u; float f; } v; v.u = (u32)b << 16; return v.f;
}

__device__ __forceinline__ u32 pack2(float lo, float hi) {
    return (u32)f2bf(lo) | ((u32)f2bf(hi) << 16);
}

__device__ __forceinline__ float lane_bcast(float v, int n) {
    union { float f; uint32_t u; } a, b;
    a.f = v;
    b.u = __builtin_amdgcn_readlane(a.u, n);
    return b.f;
}

// read bf16 fragment A[row][k0..k0+7] from pair-packed LDS tile (stride 33 dwords)
__device__ __forceinline__ short8 frag_ld(const u32* s, int row, int k0) {
    const u32* q = s + row * 33 + (k0 >> 1);
    union { u32 u[4]; short8 v; } r;
    r.u[0] = q[0]; r.u[1] = q[1]; r.u[2] = q[2]; r.u[3] = q[3];
    return r.v;
}

__device__ __forceinline__ void gload_lds16(const u16* g, u16* s) {
    __builtin_amdgcn_global_load_lds(
        (const __attribute__((address_space(1))) void*)g,
        (__attribute__((address_space(3))) void*)s,
        16, 0, 0);
}

// =====================================================================
// fused fp32 -> bf16 cast for x, W_in, W_out (one launch). n's in float4 quads.
// =====================================================================
__global__ __launch_bounds__(256) void cast3_kern(
    const float* __restrict__ s0, u16* __restrict__ d0, int n0,
    const float* __restrict__ s1, u16* __restrict__ d1, int n1,
    const float* __restrict__ s2, u16* __restrict__ d2, int n2)
{
    int i = blockIdx.x * 256 + threadIdx.x;
    const float* s; u16* d;
    if (i < n0)           { s = s0; d = d0; }
    else if (i < n0 + n1) { i -= n0; s = s1; d = d1; }
    else                  { i -= n0 + n1; if (i >= n2) return; s = s2; d = d2; }
    float4 v = ((const float4*)s)[i];
    ushort4 o;
    o.x = f2bf(v.x); o.y = f2bf(v.y); o.z = f2bf(v.z); o.w = f2bf(v.w);
    ((ushort4*)d)[i] = o;
}

// =====================================================================
// bf16 MFMA GEMM (m97 pattern), BK = 32*NP via NP 32-k LDS panels:
// one barrier pair per BK (NP=4 -> quarter the barriers of BK=32) while
// keeping each panel's 64 B row stride (2-way bank aliasing = free).
//   C = A[M,K] @ Bt[N,K]^T.  4 waves as 2x2; wave tile (BM/2)x(BN/2).
// K % (32*NP) == 0 assumed. PSPLIT: col<2176 -> bf16 projb; else f32 dtf.
// LDS: NP*(BM+BN)*64 B  (gemm1 NP=4: 73.7 KB -> 2 blocks/CU exactly).
// =====================================================================
template<int BM, int BN, int NP, bool GUARD, bool PSPLIT>
__global__ __launch_bounds__(256, 2) void gemm_mfma_bt(
    const u16* __restrict__ A, const u16* __restrict__ Bt,
    float* __restrict__ Cf, u16* __restrict__ Cb, float* __restrict__ Dt,
    int M, int N, int K)
{
    constexpr int MI = BM / 32;
    constexpr int NI = BN / 32;
    __shared__ u16 As[NP][BM * 32];
    __shared__ u16 Bs[NP][BN * 32];

    const int tid = threadIdx.x;
    const int w   = tid >> 6;
    const int ln  = tid & 63;
    const int wm  = w >> 1, wn = w & 1;
    const int bm  = blockIdx.y * BM;
    const int bn  = blockIdx.x * BN;

    const int srow = ln >> 2;          // 16 rows per wave-load group
    const int skq  = (ln & 3) * 8;
    const int fr = ln & 15;
    const int fq = (ln >> 4) * 8;

    floatx4 acc[MI][NI];
    const floatx4 fzero = {0.f, 0.f, 0.f, 0.f};
    #pragma unroll
    for (int mi = 0; mi < MI; ++mi)
        #pragma unroll
        for (int ni = 0; ni < NI; ++ni) acc[mi][ni] = fzero;

    for (int k0 = 0; k0 < K; k0 += 32 * NP) {
        #pragma unroll
        for (int p = 0; p < NP; ++p) {
            const int kp = k0 + p * 32;
            #pragma unroll
            for (int g = 0; g < BM / 16; ++g) {
                if ((g & 3) != w) continue;    // group -> wave round-robin
                gload_lds16(A + (size_t)(bm + g * 16 + srow) * K + kp + skq,
                            &As[p][g * 16 * 32]);
            }
            #pragma unroll
            for (int g = 0; g < BN / 16; ++g) {
                if ((g & 3) != w) continue;
                int rn = bn + g * 16 + srow;
                if (GUARD) rn = (rn < N) ? rn : (N - 1);
                gload_lds16(Bt + (size_t)rn * K + kp + skq,
                            &Bs[p][g * 16 * 32]);
            }
        }
        __syncthreads();

        #pragma unroll
        for (int p = 0; p < NP; ++p) {
            short8 af[MI], bf[NI];
            #pragma unroll
            for (int mi = 0; mi < MI; ++mi)
                af[mi] = *(const short8*)&As[p][(wm * (BM / 2) + mi * 16 + fr) * 32 + fq];
            #pragma unroll
            for (int ni = 0; ni < NI; ++ni)
                bf[ni] = *(const short8*)&Bs[p][(wn * (BN / 2) + ni * 16 + fr) * 32 + fq];
            #pragma unroll
            for (int mi = 0; mi < MI; ++mi)
                #pragma unroll
                for (int ni = 0; ni < NI; ++ni)
                    acc[mi][ni] = __builtin_amdgcn_mfma_f32_16x16x32_bf16(
                        af[mi], bf[ni], acc[mi][ni], 0, 0, 0);
        }
        __syncthreads();
    }

    const int cr = (ln >> 4) * 4;
    const int cc = ln & 15;
    #pragma unroll
    for (int mi = 0; mi < MI; ++mi) {
        const int row0 = bm + wm * (BM / 2) + mi * 16 + cr;
        #pragma unroll
        for (int ni = 0; ni < NI; ++ni) {
            const int col = bn + wn * (BN / 2) + ni * 16 + cc;
            #pragma unroll
            for (int r = 0; r < 4; ++r) {
                const int row = row0 + r;
                const float v = acc[mi][ni][r];
                if (PSPLIT) {
                    if (col < PB)
                        Cb[(size_t)row * PB + col] = f2bf(v);
                    else if (col < EPROJ)
                        Dt[(size_t)row * 16 + (col - PB)] = v;
                } else {
                    Cf[(size_t)row * N + col] = v;
                }
            }
        }
    }
}

// =====================================================================
// SSD phase 1 — 4-wave cooperative block per (b,h,chunk):
//   conv+silu via register sliding window over DIRECT global x reads;
//   exports conv'd X^T. La = cumsum(logdA);
//   Hc = (e^(La63-La_s) B)^T @ X (MFMA) -> stored bf16 (hb).
// =====================================================================
__global__ __launch_bounds__(256) void ssd_phase1(
    const u16* __restrict__ projb, const float* __restrict__ dtf,
    const float* __restrict__ cw, const float* __restrict__ cb,
    const float* __restrict__ A_log, const float* __restrict__ dt_bias,
    u16* __restrict__ hb, float* __restrict__ Pc, float* __restrict__ LaBuf,
    u32* __restrict__ xT)
{
    __shared__ u32 sBD[64 * 33];   // (e^(La63-La_s) B[s][n])^T : [n][s-pair]
    __shared__ u32 sXt[64 * 33];   // X^T: [p][s-pair]

    const int bid = blockIdx.x;               // ((b*16+h)*32 + c)
    const int c = bid & (NC - 1);
    const int h = (bid >> 5) & (NHEADS - 1);
    const int b = bid >> 9;
    const int tid = threadIdx.x;
    const int w = tid >> 6, ln = tid & 63;
    const int a = ln & 15, q = ln >> 4;
    const size_t r0 = (size_t)b * L_N + c * LC;

    // logdA + inclusive cumsum (redundant per wave; all waves identical)
    float dt = dtf[(r0 + ln) * 16 + h] + dt_bias[h];
    float sp = (dt > 15.f) ? dt : log1pf(__expf(dt));
    float La = sp * (-__expf(A_log[h]));
    #pragma unroll
    for (int d = 1; d < 64; d <<= 1) {
        float up = __shfl_up(La, d, 64);
        if (ln >= d) La += up;
    }
    if (w == 0) LaBuf[(size_t)bid * 64 + ln] = La;
    const float La63 = lane_bcast(La, 63);

    const int ch = h * 64 + ln;
    const float4 w4 = *(const float4*)(cw + ch * 4);
    const float bias = cb[ch];
    const u16* xcol = projb + OFF_XP + ch;     // column base for x reads
    const size_t bbase = (size_t)b * L_N;

    // rolling window: xr[0..2] = x at local rows (s-3, s-2, s-1); s0 = 16w
    float xr[3];
    #pragma unroll
    for (int i = 0; i < 3; ++i) {
        const int tl = c * LC + 16 * w - 3 + i;
        xr[i] = (tl >= 0) ? bf2f(xcol[(bbase + tl) * PB]) : 0.f;
    }

    // staging: wave w covers s-pairs [w*8, w*8+8); conv+silu inline
    #pragma unroll
    for (int j = 0; j < 8; ++j) {
        const int sp_ = w * 8 + j, s = sp_ * 2;
        const float xa = bf2f(xcol[(r0 + s) * PB]);
        const float xb = bf2f(xcol[(r0 + s + 1) * PB]);
        float a0 = bias, a1 = bias;
        a0 += xr[0] * w4.x; a0 += xr[1] * w4.y; a0 += xr[2] * w4.z; a0 += xa * w4.w;
        a1 += xr[1] * w4.x; a1 += xr[2] * w4.y; a1 += xa * w4.z;   a1 += xb * w4.w;
        xr[0] = xr[2]; xr[1] = xa; xr[2] = xb;
        const float x0 = silu_f(a0), x1 = silu_f(a1);
        const u32 xp = pack2(x0, x1);
        sXt[ln * 33 + sp_] = xp;
        xT[(size_t)bid * 2048 + sp_ * 64 + ln] = xp;   // export for phase3
        const float w0 = __expf(La63 - lane_bcast(La, s));
        const float w1 = __expf(La63 - lane_bcast(La, s + 1));
        const float b0 = bf2f(projb[(r0 + s) * PB + OFF_B + ln]) * w0;
        const float b1 = bf2f(projb[(r0 + s + 1) * PB + OFF_B + ln]) * w1;
        sBD[ln * 33 + sp_] = pack2(b0, b1);
    }
    __syncthreads();

    // MFMA: wave w computes output tile-row tm=w (rows n in [16w,16w+16))
    short8 af[2], bf[4][2];
    #pragma unroll
    for (int ks = 0; ks < 2; ++ks)
        af[ks] = frag_ld(sBD, w * 16 + a, ks * 32 + q * 8);
    #pragma unroll
    for (int tn = 0; tn < 4; ++tn)
        #pragma unroll
        for (int ks = 0; ks < 2; ++ks)
            bf[tn][ks] = frag_ld(sXt, tn * 16 + a, ks * 32 + q * 8);

    const floatx4 fzero = {0.f, 0.f, 0.f, 0.f};
    floatx4 acc[4];
    #pragma unroll
    for (int tn = 0; tn < 4; ++tn) {
        acc[tn] = fzero;
        #pragma unroll
        for (int ks = 0; ks < 2; ++ks)
            acc[tn] = __builtin_amdgcn_mfma_f32_16x16x32_bf16(
                af[ks], bf[tn][ks], acc[tn], 0, 0, 0);
    }

    u16* hp = hb + (size_t)bid * 4096;         // Hc bf16 [n][p]
    #pragma unroll
    for (int tn = 0; tn < 4; ++tn)
        #pragma unroll
        for (int r = 0; r < 4; ++r)
            hp[(w * 16 + q * 4 + r) * 64 + tn * 16 + a] = f2bf(acc[tn][r]);
    if (tid == 0) Pc[bid] = __expf(La63);
}

// =====================================================================
// SSD phase 2 — element-parallel inter-chunk carry over bf16 h-state,
// processed as u32 pairs (2 elements/thread-lane, f32 carries).
// 256 blocks x 256 threads over 32 (b,h) x 2048 pairs.
// =====================================================================
__global__ __launch_bounds__(256) void ssd_phase2(
    u32* __restrict__ hb32, const float* __restrict__ Pc)
{
    const int bid = blockIdx.x;               // bh*8 + eg
    const int bh = bid >> 3;
    const int e = (bid & 7) * 256 + threadIdx.x;    // u32 pair 0..2047
    const size_t base = (size_t)(bh * NC) * 2048 + e;

    u32 v[NC];
    #pragma unroll
    for (int c = 0; c < NC; ++c)
        v[c] = hb32[base + (size_t)c * 2048];

    float c0 = 0.f, c1 = 0.f;
    #pragma unroll
    for (int c = 0; c < NC; ++c) {
        const u32 cur = v[c];
        const float lo = bf2f((u16)cur), hi = bf2f((u16)(cur >> 16));
        v[c] = pack2(c0, c1);                  // h_start entering chunk c
        const float Pv = Pc[bh * NC + c];
        c0 = fmaf(Pv, c0, lo);
        c1 = fmaf(Pv, c1, hi);
    }

    #pragma unroll
    for (int c = 0; c < NC; ++c)
        hb32[base + (size_t)c * 2048] = v[c];
}

// =====================================================================
// SSD phase 3 — 4-wave cooperative block per (b,h,chunk):
//   X^T precomputed (phase1); h_start bf16 (phase2);
//   S^T = B @ C;  W[i][s] = S[i,s] e^(La_i-La_s) (s<=i)
//   Y = diag(e^La) C @ h_start^T + W @ X^T;  yz = Y * silu(z)
// =====================================================================
__global__ __launch_bounds__(256) void ssd_phase3(
    const u16* __restrict__ projb, const u32* __restrict__ xT,
    const u16* __restrict__ hb, const float* __restrict__ LaBuf,
    u16* __restrict__ yz)
{
    __shared__ char lds[34048];
    u32* sBW   = (u32*)lds;              // B natural, then W (aliased)
    u32* sC    = (u32*)(lds + 8448);     // C natural [i][n-pair]
    u32* sXt   = (u32*)(lds + 16896);    // X^T [p][s-pair]
    u32* sH    = (u32*)(lds + 25344);    // h_start^T [p][n-pair]
    float* sLaF = (float*)(lds + 33792); // La[64]
    float* sY  = (float*)(lds + 8448);   // f32 [i][p] 64x66, aliases sC+sXt (epilogue)

    const int bid = blockIdx.x;
    const int c = bid & (NC - 1);
    const int h = (bid >> 5) & (NHEADS - 1);
    const int b = bid >> 9;
    const int tid = threadIdx.x;
    const int w = tid >> 6, ln = tid & 63;
    const int a = ln & 15, q = ln >> 4;
    const int hw = ln >> 5, k32 = ln & 31;
    const size_t r0 = (size_t)b * L_N + c * LC;

    if (tid < 64) sLaF[tid] = LaBuf[(size_t)bid * 64 + tid];

    // single staging pass: B, C natural (raw copies); X^T copy; H^T pack
    const u16* hs = hb + (size_t)bid * 4096;
    #pragma unroll
    for (int j = 0; j < 8; ++j) {
        const int rp = w * 8 + j;
        const int row = rp * 2 + hw;
        sBW[row * 33 + k32] = *(const u32*)(projb + (r0 + row) * PB + OFF_B + 2 * k32);
        sC [row * 33 + k32] = *(const u32*)(projb + (r0 + row) * PB + OFF_C + 2 * k32);
        sXt[ln * 33 + rp] = xT[(size_t)bid * 2048 + rp * 64 + ln];
        sH [ln * 33 + rp] = (u32)hs[(2 * rp) * 64 + ln]
                          | ((u32)hs[(2 * rp + 1) * 64 + ln] << 16);
    }
    __syncthreads();

    const floatx4 fzero = {0.f, 0.f, 0.f, 0.f};

    // ---- m1: S^T tiles [tm][tn=w], tm<=w ----
    short8 cfr[2], bfr[4][2];
    #pragma unroll
    for (int ks = 0; ks < 2; ++ks)
        cfr[ks] = frag_ld(sC, w * 16 + a, ks * 32 + q * 8);
    #pragma unroll
    for (int tm = 0; tm < 4; ++tm)
        if (tm <= w)
            #pragma unroll
            for (int ks = 0; ks < 2; ++ks)
                bfr[tm][ks] = frag_ld(sBW, tm * 16 + a, ks * 32 + q * 8);
    floatx4 accS[4];
    #pragma unroll
    for (int tm = 0; tm < 4; ++tm) {
        if (tm > w) continue;
        accS[tm] = fzero;
        #pragma unroll
        for (int ks = 0; ks < 2; ++ks)
            accS[tm] = __builtin_amdgcn_mfma_f32_16x16x32_bf16(
                bfr[tm][ks], cfr[ks], accS[tm], 0, 0, 0);
    }
    __syncthreads();   // all waves done reading B before W overwrite

    // ---- build W rows i in [16w,16w+16) ----
    {
        const int i = w * 16 + a;
        const float Li = sLaF[i];
        #pragma unroll
        for (int tm = 0; tm < 4; ++tm) {
            const int d0 = i * 33 + tm * 8 + q * 2;
            if (tm > w) {
                sBW[d0] = 0; sBW[d0 + 1] = 0;
            } else {
                const float4 Ls = *(const float4*)(sLaF + tm * 16 + q * 4);
                float v[4];
                #pragma unroll
                for (int r = 0; r < 4; ++r) {
                    const int s = tm * 16 + q * 4 + r;
                    const float ww = (s <= i) ? __expf(Li - ((const float*)&Ls)[r]) : 0.f;
                    v[r] = accS[tm][r] * ww;
                }
                sBW[d0]     = pack2(v[0], v[1]);
                sBW[d0 + 1] = pack2(v[2], v[3]);
            }
        }
    }

    // ---- m4: accY = C @ h_start^T (row-tile w), scale rows by e^La_i ----
    short8 hfr[4][2];
    #pragma unroll
    for (int tp = 0; tp < 4; ++tp)
        #pragma unroll
        for (int ks = 0; ks < 2; ++ks)
            hfr[tp][ks] = frag_ld(sH, tp * 16 + a, ks * 32 + q * 8);
    floatx4 accY[4];
    #pragma unroll
    for (int tp = 0; tp < 4; ++tp) {
        accY[tp] = fzero;
        #pragma unroll
        for (int ks = 0; ks < 2; ++ks)
            accY[tp] = __builtin_amdgcn_mfma_f32_16x16x32_bf16(
                cfr[ks], hfr[tp][ks], accY[tp], 0, 0, 0);
    }
    {
        const float4 Ls = *(const float4*)(sLaF + w * 16 + q * 4);
        float e4[4];
        #pragma unroll
        for (int r = 0; r < 4; ++r) e4[r] = __expf(((const float*)&Ls)[r]);
        #pragma unroll
        for (int tp = 0; tp < 4; ++tp)
            #pragma unroll
            for (int r = 0; r < 4; ++r) accY[tp][r] *= e4[r];
    }

    // ---- m2: accY += W @ X^T (wave reads only its own W rows) ----
    short8 wfr[2], xfr[4][2];
    #pragma unroll
    for (int ks = 0; ks < 2; ++ks)
        wfr[ks] = frag_ld(sBW, w * 16 + a, ks * 32 + q * 8);
    #pragma unroll
    for (int tp = 0; tp < 4; ++tp)
        #pragma unroll
        for (int ks = 0; ks < 2; ++ks)
            xfr[tp][ks] = frag_ld(sXt, tp * 16 + a, ks * 32 + q * 8);
    #pragma unroll
    for (int tp = 0; tp < 4; ++tp)
        #pragma unroll
        for (int ks = 0; ks < 2; ++ks)
            accY[tp] = __builtin_amdgcn_mfma_f32_16x16x32_bf16(
                wfr[ks], xfr[tp][ks], accY[tp], 0, 0, 0);
    __syncthreads();   // all frag reads of sC/sXt done; safe to alias as sY

    // ---- epilogue: own-rows LDS round-trip, gate (bf16 z), bf16 store ----
    #pragma unroll
    for (int tp = 0; tp < 4; ++tp)
        #pragma unroll
        for (int r = 0; r < 4; ++r)
            sY[(w * 16 + q * 4 + r) * 66 + tp * 16 + a] = accY[tp][r];
    #pragma unroll
    for (int ii = 0; ii < 16; ++ii) {
        const int i = w * 16 + ii;
        const float y = sY[i * 66 + ln];
        const float z = bf2f(projb[(r0 + i) * PB + OFF_Z + h * 64 + ln]);
        yz[(r0 + i) * DINNER + h * 64 + ln] = f2bf(y * silu_f(z));
    }
}

// =====================================================================
extern "C" void kernel_launch(void* const* d_in, const int* in_sizes, int n_in,
                              void* d_out, int out_size, void* d_ws, size_t ws_size,
                              hipStream_t stream)
{
    const float* x       = (const float*)d_in[0];
    const float* W_in    = (const float*)d_in[1];
    const float* conv_w  = (const float*)d_in[2];
    const float* conv_b  = (const float*)d_in[3];
    const float* A_log   = (const float*)d_in[4];
    const float* dt_bias = (const float*)d_in[5];
    const float* W_out   = (const float*)d_in[6];
    float* out = (float*)d_out;

    // workspace layout (~50 MB)
    u16*   projb = (u16*)d_ws;                                  // 4096*2176 bf16
    float* dtf   = (float*)(projb + (size_t)4096 * PB);         // 4096*16 f32
    u16*   hb    = (u16*)(dtf + (size_t)4096 * 16);             // 1024*4096 bf16 (h-state)
    float* Pc    = (float*)(hb + (size_t)1024 * 4096);          // 1024
    float* LaBuf = Pc + 1024;                                   // 1024*64
    u16*   xbf   = (u16*)(LaBuf + 1024 * 64);                   // 4096*512 bf16
    u16*   wibf  = xbf + (size_t)4096 * DMODEL;                 // 2192*512 bf16
    u16*   wobf  = wibf + (size_t)EPROJ * DMODEL;               // 512*1024 bf16
    u16*   yzbf  = wobf + (size_t)DMODEL * DINNER;              // 4096*1024 bf16
    u32*   xT    = (u32*)(yzbf + (size_t)4096 * DINNER);        // 1024*2048 u32 (conv'd X^T)

    const int M = B_N * L_N;  // 4096
    const int n0 = M * DMODEL / 4, n1 = EPROJ * DMODEL / 4, n2 = DMODEL * DINNER / 4;

    // 0) fused casts
    cast3_kern<<<(n0 + n1 + n2 + 255) / 256, 256, 0, stream>>>(
        x, xbf, n0, W_in, wibf, n1, W_out, wobf, n2);

    // 1) in_proj: proj = x @ W_in^T (M=4096, N=2192, K=512)
    //    BN=160 -> 448 blocks, NP=4 (BK=128) -> 4 barrier pairs
    gemm_mfma_bt<128, 160, 4, true, true><<<dim3(14, M / 128), 256, 0, stream>>>(
        xbf, wibf, nullptr, projb, dtf, M, EPROJ, DMODEL);

    // 2) SSD chunked scan (MFMA, 4-wave cooperative; conv in p1 via register
    //    sliding window; bf16 h-state pipeline; p3 consumes p1's X^T)
    ssd_phase1<<<B_N * NHEADS * NC, 256, 0, stream>>>(
        projb, dtf, conv_w, conv_b, A_log, dt_bias, hb, Pc, LaBuf, xT);
    ssd_phase2<<<B_N * NHEADS * 8, 256, 0, stream>>>((u32*)hb, Pc);
    ssd_phase3<<<B_N * NHEADS * NC, 256, 0, stream>>>(
        projb, xT, hb, LaBuf, yzbf);

    // 3) out_proj: out = yz @ W_out^T (M=4096, N=512, K=1024),
    //    512 blocks (2/CU), NP=4 (BK=128) -> 8 barrier pairs
    gemm_mfma_bt<64, 64, 4, false, false><<<dim3(DMODEL / 64, M / 64), 256, 0, stream>>>(
        yzbf, wobf, out, nullptr, nullptr, M, DMODEL, DINNER);
}

// Round 15
// 134.183 us; speedup vs baseline: 5.0394x; 1.0209x over previous
//
#include <hip/hip_runtime.h>
#include <cstdint>
#include <cstddef>

// ---- problem constants ----
#define B_N     2
#define L_N     2048
#define DMODEL  512
#define DINNER  1024
#define DSTATE  64
#define NHEADS  16
#define EPROJ   2192      // 2*DINNER + 2*DSTATE + NHEADS
#define PB      2176      // bf16 proj row stride (z,x,B,C)
#define OFF_Z   0
#define OFF_XP  1024
#define OFF_B   2048
#define OFF_C   2112
#define LC      64        // scan chunk length (= matmul tile)
#define NC      32        // L_N / LC

typedef unsigned short u16;
typedef unsigned int   u32;
typedef __attribute__((ext_vector_type(8))) short short8;   // 8 bf16 (4 VGPRs)
typedef __attribute__((ext_vector_type(4))) float floatx4;  // MFMA acc

__device__ __forceinline__ float silu_f(float v) { return v / (1.f + __expf(-v)); }

__device__ __forceinline__ u16 f2bf(float f) {
    union { float f; uint32_t u; } v; v.f = f;
    uint32_t r = (v.u + 0x7FFFu + ((v.u >> 16) & 1u)) >> 16;  // RNE
    return (u16)r;
}

__device__ __forceinline__ float bf2f(u16 b) {
    union { u32 u; float f; } v; v.u = (u32)b << 16; return v.f;
}

__device__ __forceinline__ u32 pack2(float lo, float hi) {
    return (u32)f2bf(lo) | ((u32)f2bf(hi) << 16);
}

__device__ __forceinline__ float lane_bcast(float v, int n) {
    union { float f; uint32_t u; } a, b;
    a.f = v;
    b.u = __builtin_amdgcn_readlane(a.u, n);
    return b.f;
}

// read bf16 fragment A[row][k0..k0+7] from pair-packed LDS tile (stride 33 dwords)
__device__ __forceinline__ short8 frag_ld(const u32* s, int row, int k0) {
    const u32* q = s + row * 33 + (k0 >> 1);
    union { u32 u[4]; short8 v; } r;
    r.u[0] = q[0]; r.u[1] = q[1]; r.u[2] = q[2]; r.u[3] = q[3];
    return r.v;
}

__device__ __forceinline__ void gload_lds16(const u16* g, u16* s) {
    __builtin_amdgcn_global_load_lds(
        (const __attribute__((address_space(1))) void*)g,
        (__attribute__((address_space(3))) void*)s,
        16, 0, 0);
}

// =====================================================================
// fused fp32 -> bf16 cast for x, W_in (one launch). n's in float4 quads.
// (W_out cast is piggybacked onto ssd_phase2 — it is only needed by the
//  final GEMM and phase2 runs at 1 block/CU with idle second slots.)
// =====================================================================
__global__ __launch_bounds__(256) void cast2_kern(
    const float* __restrict__ s0, u16* __restrict__ d0, int n0,
    const float* __restrict__ s1, u16* __restrict__ d1, int n1)
{
    int i = blockIdx.x * 256 + threadIdx.x;
    const float* s; u16* d;
    if (i < n0)           { s = s0; d = d0; }
    else                  { i -= n0; if (i >= n1) return; s = s1; d = d1; }
    float4 v = ((const float4*)s)[i];
    ushort4 o;
    o.x = f2bf(v.x); o.y = f2bf(v.y); o.z = f2bf(v.z); o.w = f2bf(v.w);
    ((ushort4*)d)[i] = o;
}

// =====================================================================
// bf16 MFMA GEMM (m97 pattern), BK = 32*NP via NP 32-k LDS panels:
// one barrier pair per BK while keeping each panel's 64 B row stride
// (2-way bank aliasing = free).
//   C = A[M,K] @ Bt[N,K]^T.  4 waves as 2x2; wave tile (BM/2)x(BN/2).
// K % (32*NP) == 0 assumed. PSPLIT: col<2176 -> bf16 projb; else f32 dtf.
// LDS: NP*(BM+BN)*64 B  (gemm1 NP=4: 73.7 KB; gemm2 NP=8: 65.5 KB —
// both exactly 2 blocks/CU).
// =====================================================================
template<int BM, int BN, int NP, bool GUARD, bool PSPLIT>
__global__ __launch_bounds__(256, 2) void gemm_mfma_bt(
    const u16* __restrict__ A, const u16* __restrict__ Bt,
    float* __restrict__ Cf, u16* __restrict__ Cb, float* __restrict__ Dt,
    int M, int N, int K)
{
    constexpr int MI = BM / 32;
    constexpr int NI = BN / 32;
    __shared__ u16 As[NP][BM * 32];
    __shared__ u16 Bs[NP][BN * 32];

    const int tid = threadIdx.x;
    const int w   = tid >> 6;
    const int ln  = tid & 63;
    const int wm  = w >> 1, wn = w & 1;
    const int bm  = blockIdx.y * BM;
    const int bn  = blockIdx.x * BN;

    const int srow = ln >> 2;          // 16 rows per wave-load group
    const int skq  = (ln & 3) * 8;
    const int fr = ln & 15;
    const int fq = (ln >> 4) * 8;

    floatx4 acc[MI][NI];
    const floatx4 fzero = {0.f, 0.f, 0.f, 0.f};
    #pragma unroll
    for (int mi = 0; mi < MI; ++mi)
        #pragma unroll
        for (int ni = 0; ni < NI; ++ni) acc[mi][ni] = fzero;

    for (int k0 = 0; k0 < K; k0 += 32 * NP) {
        #pragma unroll
        for (int p = 0; p < NP; ++p) {
            const int kp = k0 + p * 32;
            #pragma unroll
            for (int g = 0; g < BM / 16; ++g) {
                if ((g & 3) != w) continue;    // group -> wave round-robin
                gload_lds16(A + (size_t)(bm + g * 16 + srow) * K + kp + skq,
                            &As[p][g * 16 * 32]);
            }
            #pragma unroll
            for (int g = 0; g < BN / 16; ++g) {
                if ((g & 3) != w) continue;
                int rn = bn + g * 16 + srow;
                if (GUARD) rn = (rn < N) ? rn : (N - 1);
                gload_lds16(Bt + (size_t)rn * K + kp + skq,
                            &Bs[p][g * 16 * 32]);
            }
        }
        __syncthreads();

        #pragma unroll
        for (int p = 0; p < NP; ++p) {
            short8 af[MI], bf[NI];
            #pragma unroll
            for (int mi = 0; mi < MI; ++mi)
                af[mi] = *(const short8*)&As[p][(wm * (BM / 2) + mi * 16 + fr) * 32 + fq];
            #pragma unroll
            for (int ni = 0; ni < NI; ++ni)
                bf[ni] = *(const short8*)&Bs[p][(wn * (BN / 2) + ni * 16 + fr) * 32 + fq];
            #pragma unroll
            for (int mi = 0; mi < MI; ++mi)
                #pragma unroll
                for (int ni = 0; ni < NI; ++ni)
                    acc[mi][ni] = __builtin_amdgcn_mfma_f32_16x16x32_bf16(
                        af[mi], bf[ni], acc[mi][ni], 0, 0, 0);
        }
        __syncthreads();
    }

    const int cr = (ln >> 4) * 4;
    const int cc = ln & 15;
    #pragma unroll
    for (int mi = 0; mi < MI; ++mi) {
        const int row0 = bm + wm * (BM / 2) + mi * 16 + cr;
        #pragma unroll
        for (int ni = 0; ni < NI; ++ni) {
            const int col = bn + wn * (BN / 2) + ni * 16 + cc;
            #pragma unroll
            for (int r = 0; r < 4; ++r) {
                const int row = row0 + r;
                const float v = acc[mi][ni][r];
                if (PSPLIT) {
                    if (col < PB)
                        Cb[(size_t)row * PB + col] = f2bf(v);
                    else if (col < EPROJ)
                        Dt[(size_t)row * 16 + (col - PB)] = v;
                } else {
                    Cf[(size_t)row * N + col] = v;
                }
            }
        }
    }
}

// =====================================================================
// SSD phase 1 — 4-wave cooperative block per (b,h,chunk):
//   conv+silu via register sliding window over DIRECT global x reads;
//   exports conv'd X^T. La = cumsum(logdA);
//   Hc = (e^(La63-La_s) B)^T @ X (MFMA) -> stored bf16 (hb).
// =====================================================================
__global__ __launch_bounds__(256) void ssd_phase1(
    const u16* __restrict__ projb, const float* __restrict__ dtf,
    const float* __restrict__ cw, const float* __restrict__ cb,
    const float* __restrict__ A_log, const float* __restrict__ dt_bias,
    u16* __restrict__ hb, float* __restrict__ Pc, float* __restrict__ LaBuf,
    u32* __restrict__ xT)
{
    __shared__ u32 sBD[64 * 33];   // (e^(La63-La_s) B[s][n])^T : [n][s-pair]
    __shared__ u32 sXt[64 * 33];   // X^T: [p][s-pair]

    const int bid = blockIdx.x;               // ((b*16+h)*32 + c)
    const int c = bid & (NC - 1);
    const int h = (bid >> 5) & (NHEADS - 1);
    const int b = bid >> 9;
    const int tid = threadIdx.x;
    const int w = tid >> 6, ln = tid & 63;
    const int a = ln & 15, q = ln >> 4;
    const size_t r0 = (size_t)b * L_N + c * LC;

    // logdA + inclusive cumsum (redundant per wave; all waves identical)
    float dt = dtf[(r0 + ln) * 16 + h] + dt_bias[h];
    float sp = (dt > 15.f) ? dt : log1pf(__expf(dt));
    float La = sp * (-__expf(A_log[h]));
    #pragma unroll
    for (int d = 1; d < 64; d <<= 1) {
        float up = __shfl_up(La, d, 64);
        if (ln >= d) La += up;
    }
    if (w == 0) LaBuf[(size_t)bid * 64 + ln] = La;
    const float La63 = lane_bcast(La, 63);

    const int ch = h * 64 + ln;
    const float4 w4 = *(const float4*)(cw + ch * 4);
    const float bias = cb[ch];
    const u16* xcol = projb + OFF_XP + ch;     // column base for x reads
    const size_t bbase = (size_t)b * L_N;

    // rolling window: xr[0..2] = x at local rows (s-3, s-2, s-1); s0 = 16w
    float xr[3];
    #pragma unroll
    for (int i = 0; i < 3; ++i) {
        const int tl = c * LC + 16 * w - 3 + i;
        xr[i] = (tl >= 0) ? bf2f(xcol[(bbase + tl) * PB]) : 0.f;
    }

    // staging: wave w covers s-pairs [w*8, w*8+8); conv+silu inline
    #pragma unroll
    for (int j = 0; j < 8; ++j) {
        const int sp_ = w * 8 + j, s = sp_ * 2;
        const float xa = bf2f(xcol[(r0 + s) * PB]);
        const float xb = bf2f(xcol[(r0 + s + 1) * PB]);
        float a0 = bias, a1 = bias;
        a0 += xr[0] * w4.x; a0 += xr[1] * w4.y; a0 += xr[2] * w4.z; a0 += xa * w4.w;
        a1 += xr[1] * w4.x; a1 += xr[2] * w4.y; a1 += xa * w4.z;   a1 += xb * w4.w;
        xr[0] = xr[2]; xr[1] = xa; xr[2] = xb;
        const float x0 = silu_f(a0), x1 = silu_f(a1);
        const u32 xp = pack2(x0, x1);
        sXt[ln * 33 + sp_] = xp;
        xT[(size_t)bid * 2048 + sp_ * 64 + ln] = xp;   // export for phase3
        const float w0 = __expf(La63 - lane_bcast(La, s));
        const float w1 = __expf(La63 - lane_bcast(La, s + 1));
        const float b0 = bf2f(projb[(r0 + s) * PB + OFF_B + ln]) * w0;
        const float b1 = bf2f(projb[(r0 + s + 1) * PB + OFF_B + ln]) * w1;
        sBD[ln * 33 + sp_] = pack2(b0, b1);
    }
    __syncthreads();

    // MFMA: wave w computes output tile-row tm=w (rows n in [16w,16w+16))
    short8 af[2], bf[4][2];
    #pragma unroll
    for (int ks = 0; ks < 2; ++ks)
        af[ks] = frag_ld(sBD, w * 16 + a, ks * 32 + q * 8);
    #pragma unroll
    for (int tn = 0; tn < 4; ++tn)
        #pragma unroll
        for (int ks = 0; ks < 2; ++ks)
            bf[tn][ks] = frag_ld(sXt, tn * 16 + a, ks * 32 + q * 8);

    const floatx4 fzero = {0.f, 0.f, 0.f, 0.f};
    floatx4 acc[4];
    #pragma unroll
    for (int tn = 0; tn < 4; ++tn) {
        acc[tn] = fzero;
        #pragma unroll
        for (int ks = 0; ks < 2; ++ks)
            acc[tn] = __builtin_amdgcn_mfma_f32_16x16x32_bf16(
                af[ks], bf[tn][ks], acc[tn], 0, 0, 0);
    }

    u16* hp = hb + (size_t)bid * 4096;         // Hc bf16 [n][p]
    #pragma unroll
    for (int tn = 0; tn < 4; ++tn)
        #pragma unroll
        for (int r = 0; r < 4; ++r)
            hp[(w * 16 + q * 4 + r) * 64 + tn * 16 + a] = f2bf(acc[tn][r]);
    if (tid == 0) Pc[bid] = __expf(La63);
}

// =====================================================================
// SSD phase 2 — element-parallel inter-chunk carry over bf16 h-state
// (u32 pairs, f32 carries). Blocks [0,256): carry. Blocks [256,...):
// piggybacked W_out fp32->bf16 cast (fills the idle 2nd block/CU slot).
// =====================================================================
__global__ __launch_bounds__(256) void ssd_phase2(
    u32* __restrict__ hb32, const float* __restrict__ Pc,
    const float* __restrict__ wsrc, u16* __restrict__ wdst, int nw)
{
    const int bid = blockIdx.x;
    if (bid >= 256) {
        const int i = (bid - 256) * 256 + threadIdx.x;
        if (i < nw) {
            float4 v = ((const float4*)wsrc)[i];
            ushort4 o;
            o.x = f2bf(v.x); o.y = f2bf(v.y); o.z = f2bf(v.z); o.w = f2bf(v.w);
            ((ushort4*)wdst)[i] = o;
        }
        return;
    }

    const int bh = bid >> 3;
    const int e = (bid & 7) * 256 + threadIdx.x;    // u32 pair 0..2047
    const size_t base = (size_t)(bh * NC) * 2048 + e;

    u32 v[NC];
    #pragma unroll
    for (int c = 0; c < NC; ++c)
        v[c] = hb32[base + (size_t)c * 2048];

    float c0 = 0.f, c1 = 0.f;
    #pragma unroll
    for (int c = 0; c < NC; ++c) {
        const u32 cur = v[c];
        const float lo = bf2f((u16)cur), hi = bf2f((u16)(cur >> 16));
        v[c] = pack2(c0, c1);                  // h_start entering chunk c
        const float Pv = Pc[bh * NC + c];
        c0 = fmaf(Pv, c0, lo);
        c1 = fmaf(Pv, c1, hi);
    }

    #pragma unroll
    for (int c = 0; c < NC; ++c)
        hb32[base + (size_t)c * 2048] = v[c];
}

// =====================================================================
// SSD phase 3 — 4-wave cooperative block per (b,h,chunk):
//   X^T precomputed (phase1); h_start bf16 (phase2);
//   S^T = B @ C;  W[i][s] = S[i,s] e^(La_i-La_s) (s<=i)
//   Y = diag(e^La) C @ h_start^T + W @ X^T;  yz = Y * silu(z)
// =====================================================================
__global__ __launch_bounds__(256) void ssd_phase3(
    const u16* __restrict__ projb, const u32* __restrict__ xT,
    const u16* __restrict__ hb, const float* __restrict__ LaBuf,
    u16* __restrict__ yz)
{
    __shared__ char lds[34048];
    u32* sBW   = (u32*)lds;              // B natural, then W (aliased)
    u32* sC    = (u32*)(lds + 8448);     // C natural [i][n-pair]
    u32* sXt   = (u32*)(lds + 16896);    // X^T [p][s-pair]
    u32* sH    = (u32*)(lds + 25344);    // h_start^T [p][n-pair]
    float* sLaF = (float*)(lds + 33792); // La[64]
    float* sY  = (float*)(lds + 8448);   // f32 [i][p] 64x66, aliases sC+sXt (epilogue)

    const int bid = blockIdx.x;
    const int c = bid & (NC - 1);
    const int h = (bid >> 5) & (NHEADS - 1);
    const int b = bid >> 9;
    const int tid = threadIdx.x;
    const int w = tid >> 6, ln = tid & 63;
    const int a = ln & 15, q = ln >> 4;
    const int hw = ln >> 5, k32 = ln & 31;
    const size_t r0 = (size_t)b * L_N + c * LC;

    if (tid < 64) sLaF[tid] = LaBuf[(size_t)bid * 64 + tid];

    // single staging pass: B, C natural (raw copies); X^T copy; H^T pack
    const u16* hs = hb + (size_t)bid * 4096;
    #pragma unroll
    for (int j = 0; j < 8; ++j) {
        const int rp = w * 8 + j;
        const int row = rp * 2 + hw;
        sBW[row * 33 + k32] = *(const u32*)(projb + (r0 + row) * PB + OFF_B + 2 * k32);
        sC [row * 33 + k32] = *(const u32*)(projb + (r0 + row) * PB + OFF_C + 2 * k32);
        sXt[ln * 33 + rp] = xT[(size_t)bid * 2048 + rp * 64 + ln];
        sH [ln * 33 + rp] = (u32)hs[(2 * rp) * 64 + ln]
                          | ((u32)hs[(2 * rp + 1) * 64 + ln] << 16);
    }
    __syncthreads();

    const floatx4 fzero = {0.f, 0.f, 0.f, 0.f};

    // ---- m1: S^T tiles [tm][tn=w], tm<=w ----
    short8 cfr[2], bfr[4][2];
    #pragma unroll
    for (int ks = 0; ks < 2; ++ks)
        cfr[ks] = frag_ld(sC, w * 16 + a, ks * 32 + q * 8);
    #pragma unroll
    for (int tm = 0; tm < 4; ++tm)
        if (tm <= w)
            #pragma unroll
            for (int ks = 0; ks < 2; ++ks)
                bfr[tm][ks] = frag_ld(sBW, tm * 16 + a, ks * 32 + q * 8);
    floatx4 accS[4];
    #pragma unroll
    for (int tm = 0; tm < 4; ++tm) {
        if (tm > w) continue;
        accS[tm] = fzero;
        #pragma unroll
        for (int ks = 0; ks < 2; ++ks)
            accS[tm] = __builtin_amdgcn_mfma_f32_16x16x32_bf16(
                bfr[tm][ks], cfr[ks], accS[tm], 0, 0, 0);
    }
    __syncthreads();   // all waves done reading B before W overwrite

    // ---- build W rows i in [16w,16w+16) ----
    {
        const int i = w * 16 + a;
        const float Li = sLaF[i];
        #pragma unroll
        for (int tm = 0; tm < 4; ++tm) {
            const int d0 = i * 33 + tm * 8 + q * 2;
            if (tm > w) {
                sBW[d0] = 0; sBW[d0 + 1] = 0;
            } else {
                const float4 Ls = *(const float4*)(sLaF + tm * 16 + q * 4);
                float v[4];
                #pragma unroll
                for (int r = 0; r < 4; ++r) {
                    const int s = tm * 16 + q * 4 + r;
                    const float ww = (s <= i) ? __expf(Li - ((const float*)&Ls)[r]) : 0.f;
                    v[r] = accS[tm][r] * ww;
                }
                sBW[d0]     = pack2(v[0], v[1]);
                sBW[d0 + 1] = pack2(v[2], v[3]);
            }
        }
    }

    // ---- m4: accY = C @ h_start^T (row-tile w), scale rows by e^La_i ----
    short8 hfr[4][2];
    #pragma unroll
    for (int tp = 0; tp < 4; ++tp)
        #pragma unroll
        for (int ks = 0; ks < 2; ++ks)
            hfr[tp][ks] = frag_ld(sH, tp * 16 + a, ks * 32 + q * 8);
    floatx4 accY[4];
    #pragma unroll
    for (int tp = 0; tp < 4; ++tp) {
        accY[tp] = fzero;
        #pragma unroll
        for (int ks = 0; ks < 2; ++ks)
            accY[tp] = __builtin_amdgcn_mfma_f32_16x16x32_bf16(
                cfr[ks], hfr[tp][ks], accY[tp], 0, 0, 0);
    }
    {
        const float4 Ls = *(const float4*)(sLaF + w * 16 + q * 4);
        float e4[4];
        #pragma unroll
        for (int r = 0; r < 4; ++r) e4[r] = __expf(((const float*)&Ls)[r]);
        #pragma unroll
        for (int tp = 0; tp < 4; ++tp)
            #pragma unroll
            for (int r = 0; r < 4; ++r) accY[tp][r] *= e4[r];
    }

    // ---- m2: accY += W @ X^T (wave reads only its own W rows) ----
    short8 wfr[2], xfr[4][2];
    #pragma unroll
    for (int ks = 0; ks < 2; ++ks)
        wfr[ks] = frag_ld(sBW, w * 16 + a, ks * 32 + q * 8);
    #pragma unroll
    for (int tp = 0; tp < 4; ++tp)
        #pragma unroll
        for (int ks = 0; ks < 2; ++ks)
            xfr[tp][ks] = frag_ld(sXt, tp * 16 + a, ks * 32 + q * 8);
    #pragma unroll
    for (int tp = 0; tp < 4; ++tp)
        #pragma unroll
        for (int ks = 0; ks < 2; ++ks)
            accY[tp] = __builtin_amdgcn_mfma_f32_16x16x32_bf16(
                wfr[ks], xfr[tp][ks], accY[tp], 0, 0, 0);
    __syncthreads();   // all frag reads of sC/sXt done; safe to alias as sY

    // ---- epilogue: own-rows LDS round-trip, gate (bf16 z), bf16 store ----
    #pragma unroll
    for (int tp = 0; tp < 4; ++tp)
        #pragma unroll
        for (int r = 0; r < 4; ++r)
            sY[(w * 16 + q * 4 + r) * 66 + tp * 16 + a] = accY[tp][r];
    #pragma unroll
    for (int ii = 0; ii < 16; ++ii) {
        const int i = w * 16 + ii;
        const float y = sY[i * 66 + ln];
        const float z = bf2f(projb[(r0 + i) * PB + OFF_Z + h * 64 + ln]);
        yz[(r0 + i) * DINNER + h * 64 + ln] = f2bf(y * silu_f(z));
    }
}

// =====================================================================
extern "C" void kernel_launch(void* const* d_in, const int* in_sizes, int n_in,
                              void* d_out, int out_size, void* d_ws, size_t ws_size,
                              hipStream_t stream)
{
    const float* x       = (const float*)d_in[0];
    const float* W_in    = (const float*)d_in[1];
    const float* conv_w  = (const float*)d_in[2];
    const float* conv_b  = (const float*)d_in[3];
    const float* A_log   = (const float*)d_in[4];
    const float* dt_bias = (const float*)d_in[5];
    const float* W_out   = (const float*)d_in[6];
    float* out = (float*)d_out;

    // workspace layout (~50 MB)
    u16*   projb = (u16*)d_ws;                                  // 4096*2176 bf16
    float* dtf   = (float*)(projb + (size_t)4096 * PB);         // 4096*16 f32
    u16*   hb    = (u16*)(dtf + (size_t)4096 * 16);             // 1024*4096 bf16 (h-state)
    float* Pc    = (float*)(hb + (size_t)1024 * 4096);          // 1024
    float* LaBuf = Pc + 1024;                                   // 1024*64
    u16*   xbf   = (u16*)(LaBuf + 1024 * 64);                   // 4096*512 bf16
    u16*   wibf  = xbf + (size_t)4096 * DMODEL;                 // 2192*512 bf16
    u16*   wobf  = wibf + (size_t)EPROJ * DMODEL;               // 512*1024 bf16
    u16*   yzbf  = wobf + (size_t)DMODEL * DINNER;              // 4096*1024 bf16
    u32*   xT    = (u32*)(yzbf + (size_t)4096 * DINNER);        // 1024*2048 u32 (conv'd X^T)

    const int M = B_N * L_N;  // 4096
    const int n0 = M * DMODEL / 4, n1 = EPROJ * DMODEL / 4, n2 = DMODEL * DINNER / 4;

    // 0) fused casts (x, W_in; W_out is piggybacked onto phase2)
    cast2_kern<<<(n0 + n1 + 255) / 256, 256, 0, stream>>>(
        x, xbf, n0, W_in, wibf, n1);

    // 1) in_proj: proj = x @ W_in^T (M=4096, N=2192, K=512)
    //    BN=160 -> 448 blocks, NP=4 (BK=128) -> 4 barrier pairs
    gemm_mfma_bt<128, 160, 4, true, true><<<dim3(14, M / 128), 256, 0, stream>>>(
        xbf, wibf, nullptr, projb, dtf, M, EPROJ, DMODEL);

    // 2) SSD chunked scan (MFMA, 4-wave cooperative; conv in p1 via register
    //    sliding window; bf16 h-state pipeline; p3 consumes p1's X^T)
    ssd_phase1<<<B_N * NHEADS * NC, 256, 0, stream>>>(
        projb, dtf, conv_w, conv_b, A_log, dt_bias, hb, Pc, LaBuf, xT);
    ssd_phase2<<<256 + (n2 + 255) / 256, 256, 0, stream>>>(
        (u32*)hb, Pc, W_out, wobf, n2);
    ssd_phase3<<<B_N * NHEADS * NC, 256, 0, stream>>>(
        projb, xT, hb, LaBuf, yzbf);

    // 3) out_proj: out = yz @ W_out^T (M=4096, N=512, K=1024),
    //    512 blocks (2/CU), NP=8 (BK=256) -> 4 barrier pairs
    gemm_mfma_bt<64, 64, 8, false, false><<<dim3(DMODEL / 64, M / 64), 256, 0, stream>>>(
        yzbf, wobf, out, nullptr, nullptr, M, DMODEL, DINNER);
}